// Round 1
// baseline (1235.636 us; speedup 1.0000x reference)
//
#include <hip/hip_runtime.h>
#include <hip/hip_bf16.h>

// ---------------- problem constants ----------------
#define BB 2
#define TT 2048
#define DD 1024
#define FF 4096
#define VV 256
#define HH 16
#define HD 64
#define MM (BB * TT)      // 4096 rows
#define LOCAL_W 128
#define STRIDE_G 256

typedef short s16x8 __attribute__((ext_vector_type(8)));
typedef __bf16 bf16x8 __attribute__((ext_vector_type(8)));
typedef float f32x4 __attribute__((ext_vector_type(4)));

__device__ __forceinline__ float b2f(unsigned short u) {
  return __builtin_bit_cast(float, (unsigned int)u << 16);
}
__device__ __forceinline__ unsigned short f2b(float f) {
  __hip_bfloat16 h = __float2bfloat16(f);  // RNE
  return __builtin_bit_cast(unsigned short, h);
}

// ---------------- weight transpose f32[K][N] -> bf16[N][K] ----------------
__global__ __launch_bounds__(256) void transpose_k(const float* __restrict__ W,
                                                   unsigned short* __restrict__ WT,
                                                   int K, int N) {
  __shared__ float t[32][33];
  const int n0 = blockIdx.x * 32, k0 = blockIdx.y * 32;
  const int tx = threadIdx.x, ty = threadIdx.y;  // (32, 8)
  for (int r = ty; r < 32; r += 8) t[r][tx] = W[(size_t)(k0 + r) * N + n0 + tx];
  __syncthreads();
  for (int r = ty; r < 32; r += 8)
    WT[(size_t)(n0 + r) * K + k0 + tx] = f2b(t[tx][r]);
}

// ---------------- embedding + positional ----------------
__global__ __launch_bounds__(256) void embed_kernel(const int* __restrict__ x,
                                                    const float* __restrict__ emb,
                                                    const float* __restrict__ pos,
                                                    float* __restrict__ h) {
  const int row = blockIdx.x;
  const int c = threadIdx.x * 4;
  const int tok = x[row];
  const int t = row & (TT - 1);
  float4 e = *(const float4*)&emb[(size_t)tok * DD + c];
  float4 p = *(const float4*)&pos[(size_t)t * DD + c];
  e.x += p.x; e.y += p.y; e.z += p.z; e.w += p.w;
  *(float4*)&h[(size_t)row * DD + c] = e;
}

// ---------------- layernorm f32 -> bf16 ----------------
__global__ __launch_bounds__(256) void ln_kernel(const float* __restrict__ x,
                                                 const float* __restrict__ g,
                                                 const float* __restrict__ be,
                                                 unsigned short* __restrict__ out) {
  const int row = blockIdx.x;
  const int tid = threadIdx.x;
  const float4 v = *(const float4*)&x[(size_t)row * DD + tid * 4];
  float s = v.x + v.y + v.z + v.w;
  float sq = v.x * v.x + v.y * v.y + v.z * v.z + v.w * v.w;
#pragma unroll
  for (int off = 32; off; off >>= 1) {
    s += __shfl_xor(s, off);
    sq += __shfl_xor(sq, off);
  }
  __shared__ float ss[4], ssq[4];
  const int w = tid >> 6, lane = tid & 63;
  if (lane == 0) { ss[w] = s; ssq[w] = sq; }
  __syncthreads();
  s = ss[0] + ss[1] + ss[2] + ss[3];
  sq = ssq[0] + ssq[1] + ssq[2] + ssq[3];
  const float mean = s * (1.0f / DD);
  const float var = sq * (1.0f / DD) - mean * mean;
  const float rstd = rsqrtf(var + 1e-5f);
  const float4 gv = *(const float4*)&g[tid * 4];
  const float4 bv = *(const float4*)&be[tid * 4];
  ushort4 o;
  o.x = f2b((v.x - mean) * rstd * gv.x + bv.x);
  o.y = f2b((v.y - mean) * rstd * gv.y + bv.y);
  o.z = f2b((v.z - mean) * rstd * gv.z + bv.z);
  o.w = f2b((v.w - mean) * rstd * gv.w + bv.w);
  *(ushort4*)&out[(size_t)row * DD + tid * 4] = o;
}

// ---------------- bf16 MFMA GEMM: C = A[M,K] @ BT[N,K]^T (+bias, epilogue) ----
// EPI: 0 = f32 out (+bias if nonnull)
//      1 = bf16 out (+bias)
//      2 = f32 out (+bias + res)   (residual add; out may alias res)
//      3 = bf16 out, exact GELU(acc+bias)
template <int EPI>
__global__ __launch_bounds__(256) void gemm_bt(const unsigned short* __restrict__ A,
                                               const unsigned short* __restrict__ BT,
                                               const float* __restrict__ bias,
                                               const float* __restrict__ res,
                                               void* __restrict__ outp,
                                               int M, int N, int K) {
  __shared__ unsigned short As[128 * 32];
  __shared__ unsigned short Bs[128 * 32];
  const int tid = threadIdx.x;
  const int lane = tid & 63;
  const int w = tid >> 6;
  const int n0 = blockIdx.x * 128, m0 = blockIdx.y * 128;
  const int wm = w & 1, wn = w >> 1;  // wave -> 64x64 quadrant
  f32x4 acc[4][4] = {};
  const int srow = tid >> 2;        // 0..63
  const int scol = (tid & 3) * 8;   // 0,8,16,24 (elements)

  for (int k0 = 0; k0 < K; k0 += 32) {
    if (k0) __syncthreads();  // protect LDS from overwrite while prev iter reads
#pragma unroll
    for (int c = 0; c < 2; c++) {
      const int row = c * 64 + srow;
      *(s16x8*)&As[row * 32 + scol] =
          *(const s16x8*)&A[(size_t)(m0 + row) * K + k0 + scol];
      *(s16x8*)&Bs[row * 32 + scol] =
          *(const s16x8*)&BT[(size_t)(n0 + row) * K + k0 + scol];
    }
    __syncthreads();
    bf16x8 af[4], bfr[4];
#pragma unroll
    for (int m = 0; m < 4; m++)
      af[m] = __builtin_bit_cast(
          bf16x8, *(const s16x8*)&As[(wm * 64 + m * 16 + (lane & 15)) * 32 + (lane >> 4) * 8]);
#pragma unroll
    for (int n = 0; n < 4; n++)
      bfr[n] = __builtin_bit_cast(
          bf16x8, *(const s16x8*)&Bs[(wn * 64 + n * 16 + (lane & 15)) * 32 + (lane >> 4) * 8]);
#pragma unroll
    for (int m = 0; m < 4; m++)
#pragma unroll
      for (int n = 0; n < 4; n++)
        acc[m][n] = __builtin_amdgcn_mfma_f32_16x16x32_bf16(af[m], bfr[n], acc[m][n], 0, 0, 0);
  }

  const int r0 = (lane >> 4) * 4;
  const int cc = lane & 15;
#pragma unroll
  for (int m = 0; m < 4; m++) {
#pragma unroll
    for (int n = 0; n < 4; n++) {
#pragma unroll
      for (int r = 0; r < 4; r++) {
        const int row = m0 + wm * 64 + m * 16 + r0 + r;
        const int col = n0 + wn * 64 + n * 16 + cc;
        const size_t idx = (size_t)row * N + col;
        float val = acc[m][n][r] + (bias ? bias[col] : 0.0f);
        if (EPI == 0) {
          ((float*)outp)[idx] = val;
        } else if (EPI == 1) {
          ((unsigned short*)outp)[idx] = f2b(val);
        } else if (EPI == 2) {
          ((float*)outp)[idx] = val + res[idx];
        } else {
          const float gv = 0.5f * val * (1.0f + erff(val * 0.70710678118654752f));
          ((unsigned short*)outp)[idx] = f2b(gv);
        }
      }
    }
  }
}

// ---------------- sparse attention: wave per query row ----------------
// allowed j for query i: local window [max(0,i-128), i]  plus  globals
// j%256==0 with j <= i-129 (globals inside the window are already covered).
__global__ __launch_bounds__(256) void attn_kernel(const unsigned short* __restrict__ q,
                                                   const unsigned short* __restrict__ k,
                                                   const unsigned short* __restrict__ v,
                                                   unsigned short* __restrict__ out) {
  __shared__ float qs[4][HD];
  __shared__ float ps[4][160];
  const int wid = threadIdx.x >> 6, lane = threadIdx.x & 63;
  const int gid = blockIdx.x * 4 + wid;   // (b, h, i) flattened
  const int i = gid & (TT - 1);
  const int bh = gid >> 11;               // T = 2^11
  const int h = bh & (HH - 1);
  const int b = bh >> 4;
  const size_t base = (size_t)(b * TT) * DD + (size_t)h * HD;  // head slice base

  qs[wid][lane] = b2f(q[base + (size_t)i * DD + lane]) * 0.125f;  // fold 1/sqrt(64)
  __syncthreads();

  const int lo = (i > LOCAL_W) ? i - LOCAL_W : 0;
  const int nloc = i - lo + 1;
  const int nglob = (i >= LOCAL_W + 1) ? ((i - (LOCAL_W + 1)) / STRIDE_G + 1) : 0;
  const int ntot = nloc + nglob;

  float mloc = -1e30f;
  for (int a = lane; a < ntot; a += 64) {
    const int j = (a < nglob) ? a * STRIDE_G : lo + (a - nglob);
    const unsigned short* kp = &k[base + (size_t)j * DD];
    float s = 0.f;
#pragma unroll
    for (int d = 0; d < HD; d += 4) {
      const float4 qv = *(const float4*)&qs[wid][d];
      const ushort4 kv = *(const ushort4*)(kp + d);
      s += qv.x * b2f(kv.x) + qv.y * b2f(kv.y) + qv.z * b2f(kv.z) + qv.w * b2f(kv.w);
    }
    ps[wid][a] = s;
    mloc = fmaxf(mloc, s);
  }
#pragma unroll
  for (int off = 32; off; off >>= 1) mloc = fmaxf(mloc, __shfl_xor(mloc, off));

  float lsum = 0.f;
  for (int a = lane; a < ntot; a += 64) {
    const float p = __expf(ps[wid][a] - mloc);
    ps[wid][a] = p;
    lsum += p;
  }
#pragma unroll
  for (int off = 32; off; off >>= 1) lsum += __shfl_xor(lsum, off);
  __syncthreads();

  float acc = 0.f;
  const unsigned short* vb = &v[base + lane];
  for (int a = 0; a < ntot; a++) {
    const int j = (a < nglob) ? a * STRIDE_G : lo + (a - nglob);
    acc += ps[wid][a] * b2f(vb[(size_t)j * DD]);
  }
  out[base + (size_t)i * DD + lane] = f2b(acc / lsum);
}

// ---------------- host ----------------
extern "C" void kernel_launch(void* const* d_in, const int* in_sizes, int n_in,
                              void* d_out, int out_size, void* d_ws, size_t ws_size,
                              hipStream_t stream) {
  const int* x = (const int*)d_in[0];
  const float* embed = (const float*)d_in[1];
  const float* pos = (const float*)d_in[2];
  const float* Wq = (const float*)d_in[3];
  const float* bq = (const float*)d_in[4];
  const float* Wk = (const float*)d_in[5];
  const float* bk = (const float*)d_in[6];
  const float* Wv = (const float*)d_in[7];
  const float* bv = (const float*)d_in[8];
  const float* Wo = (const float*)d_in[9];
  const float* bo = (const float*)d_in[10];
  const float* g1 = (const float*)d_in[11];
  const float* be1 = (const float*)d_in[12];
  const float* W1 = (const float*)d_in[13];
  const float* bf1 = (const float*)d_in[14];
  const float* W2 = (const float*)d_in[15];
  const float* bf2 = (const float*)d_in[16];
  const float* g2 = (const float*)d_in[17];
  const float* be2 = (const float*)d_in[18];
  const float* gf = (const float*)d_in[19];
  const float* bef = (const float*)d_in[20];
  const float* Whead = (const float*)d_in[21];

  char* ws = (char*)d_ws;
  size_t off = 0;
  auto alloc = [&](size_t bytes) -> void* {
    void* p = ws + off;
    off += (bytes + 255) & ~(size_t)255;
    return p;
  };
  unsigned short* WqT = (unsigned short*)alloc((size_t)2 * DD * DD * 2);
  unsigned short* WkT = (unsigned short*)alloc((size_t)2 * DD * DD * 2);
  unsigned short* WvT = (unsigned short*)alloc((size_t)2 * DD * DD * 2);
  unsigned short* WoT = (unsigned short*)alloc((size_t)2 * DD * DD * 2);
  unsigned short* W1T = (unsigned short*)alloc((size_t)2 * DD * FF * 2);
  unsigned short* W2T = (unsigned short*)alloc((size_t)2 * DD * FF * 2);
  unsigned short* WheadT = (unsigned short*)alloc((size_t)DD * VV * 2);
  float* h = (float*)alloc((size_t)MM * DD * 4);
  unsigned short* hn = (unsigned short*)alloc((size_t)MM * DD * 2);
  unsigned short* qb = (unsigned short*)alloc((size_t)MM * DD * 2);
  unsigned short* kb = (unsigned short*)alloc((size_t)MM * DD * 2);
  unsigned short* vb = (unsigned short*)alloc((size_t)MM * DD * 2);
  unsigned short* attnb = (unsigned short*)alloc((size_t)MM * DD * 2);
  unsigned short* mid = (unsigned short*)alloc((size_t)MM * FF * 2);
  (void)ws_size;

  const dim3 tb(32, 8);
  for (int l = 0; l < 2; l++) {
    const size_t wo = (size_t)l * DD * DD;
    const size_t wf = (size_t)l * DD * FF;
    transpose_k<<<dim3(DD / 32, DD / 32), tb, 0, stream>>>(Wq + wo, WqT + wo, DD, DD);
    transpose_k<<<dim3(DD / 32, DD / 32), tb, 0, stream>>>(Wk + wo, WkT + wo, DD, DD);
    transpose_k<<<dim3(DD / 32, DD / 32), tb, 0, stream>>>(Wv + wo, WvT + wo, DD, DD);
    transpose_k<<<dim3(DD / 32, DD / 32), tb, 0, stream>>>(Wo + wo, WoT + wo, DD, DD);
    transpose_k<<<dim3(FF / 32, DD / 32), tb, 0, stream>>>(W1 + wf, W1T + wf, DD, FF);
    transpose_k<<<dim3(DD / 32, FF / 32), tb, 0, stream>>>(W2 + wf, W2T + wf, FF, DD);
  }
  transpose_k<<<dim3(VV / 32, DD / 32), tb, 0, stream>>>(Whead, WheadT, DD, VV);

  embed_kernel<<<MM, 256, 0, stream>>>(x, embed, pos, h);

  const dim3 gq(DD / 128, MM / 128);
  for (int l = 0; l < 2; l++) {
    const size_t wo = (size_t)l * DD * DD;
    const size_t wf = (size_t)l * DD * FF;
    ln_kernel<<<MM, 256, 0, stream>>>(h, g1 + l * DD, be1 + l * DD, hn);
    gemm_bt<1><<<gq, 256, 0, stream>>>(hn, WqT + wo, bq + l * DD, nullptr, qb, MM, DD, DD);
    gemm_bt<1><<<gq, 256, 0, stream>>>(hn, WkT + wo, bk + l * DD, nullptr, kb, MM, DD, DD);
    gemm_bt<1><<<gq, 256, 0, stream>>>(hn, WvT + wo, bv + l * DD, nullptr, vb, MM, DD, DD);
    attn_kernel<<<BB * HH * TT / 4, 256, 0, stream>>>(qb, kb, vb, attnb);
    gemm_bt<2><<<gq, 256, 0, stream>>>(attnb, WoT + wo, bo + l * DD, h, h, MM, DD, DD);
    ln_kernel<<<MM, 256, 0, stream>>>(h, g2 + l * DD, be2 + l * DD, hn);
    gemm_bt<3><<<dim3(FF / 128, MM / 128), 256, 0, stream>>>(hn, W1T + wf, bf1 + l * FF,
                                                             nullptr, mid, MM, FF, DD);
    gemm_bt<2><<<gq, 256, 0, stream>>>(mid, W2T + wf, bf2 + l * DD, h, h, MM, DD, FF);
  }
  ln_kernel<<<MM, 256, 0, stream>>>(h, gf, bef, hn);
  gemm_bt<0><<<dim3(VV / 128, MM / 128), 256, 0, stream>>>(hn, WheadT, nullptr, nullptr,
                                                           d_out, MM, VV, DD);
}

// Round 2
// 752.680 us; speedup vs baseline: 1.6416x; 1.6416x over previous
//
#include <hip/hip_runtime.h>
#include <hip/hip_bf16.h>

// ---------------- problem constants ----------------
#define BB 2
#define TT 2048
#define DD 1024
#define FF 4096
#define VV 256
#define HH 16
#define HD 64
#define MM (BB * TT)      // 4096 rows
#define LOCAL_W 128
#define STRIDE_G 256

typedef short s16x8 __attribute__((ext_vector_type(8)));
typedef __bf16 bf16x8 __attribute__((ext_vector_type(8)));
typedef float f32x4 __attribute__((ext_vector_type(4)));

__device__ __forceinline__ float b2f(unsigned short u) {
  return __builtin_bit_cast(float, (unsigned int)u << 16);
}
__device__ __forceinline__ unsigned short f2b(float f) {
  __hip_bfloat16 h = __float2bfloat16(f);  // RNE
  return __builtin_bit_cast(unsigned short, h);
}
// async global->LDS, 16B per lane; LDS dest = uniform base + lane*16
__device__ __forceinline__ void gl_lds16(const unsigned short* g, unsigned short* l) {
  __builtin_amdgcn_global_load_lds(
      (const __attribute__((address_space(1))) void*)g,
      (__attribute__((address_space(3))) void*)l, 16, 0, 0);
}

// ---------------- weight transpose f32[K][N] -> bf16[N][K] ----------------
__global__ __launch_bounds__(256) void transpose_k(const float* __restrict__ W,
                                                   unsigned short* __restrict__ WT,
                                                   int K, int N) {
  __shared__ float t[32][33];
  const int n0 = blockIdx.x * 32, k0 = blockIdx.y * 32;
  const int tx = threadIdx.x, ty = threadIdx.y;  // (32, 8)
  for (int r = ty; r < 32; r += 8) t[r][tx] = W[(size_t)(k0 + r) * N + n0 + tx];
  __syncthreads();
  for (int r = ty; r < 32; r += 8)
    WT[(size_t)(n0 + r) * K + k0 + tx] = f2b(t[tx][r]);
}

// ---------------- embedding + positional ----------------
__global__ __launch_bounds__(256) void embed_kernel(const int* __restrict__ x,
                                                    const float* __restrict__ emb,
                                                    const float* __restrict__ pos,
                                                    float* __restrict__ h) {
  const int row = blockIdx.x;
  const int c = threadIdx.x * 4;
  const int tok = x[row];
  const int t = row & (TT - 1);
  float4 e = *(const float4*)&emb[(size_t)tok * DD + c];
  float4 p = *(const float4*)&pos[(size_t)t * DD + c];
  e.x += p.x; e.y += p.y; e.z += p.z; e.w += p.w;
  *(float4*)&h[(size_t)row * DD + c] = e;
}

// ---------------- layernorm f32 -> bf16 ----------------
__global__ __launch_bounds__(256) void ln_kernel(const float* __restrict__ x,
                                                 const float* __restrict__ g,
                                                 const float* __restrict__ be,
                                                 unsigned short* __restrict__ out) {
  const int row = blockIdx.x;
  const int tid = threadIdx.x;
  const float4 v = *(const float4*)&x[(size_t)row * DD + tid * 4];
  float s = v.x + v.y + v.z + v.w;
  float sq = v.x * v.x + v.y * v.y + v.z * v.z + v.w * v.w;
#pragma unroll
  for (int off = 32; off; off >>= 1) {
    s += __shfl_xor(s, off);
    sq += __shfl_xor(sq, off);
  }
  __shared__ float ss[4], ssq[4];
  const int w = tid >> 6, lane = tid & 63;
  if (lane == 0) { ss[w] = s; ssq[w] = sq; }
  __syncthreads();
  s = ss[0] + ss[1] + ss[2] + ss[3];
  sq = ssq[0] + ssq[1] + ssq[2] + ssq[3];
  const float mean = s * (1.0f / DD);
  const float var = sq * (1.0f / DD) - mean * mean;
  const float rstd = rsqrtf(var + 1e-5f);
  const float4 gv = *(const float4*)&g[tid * 4];
  const float4 bv = *(const float4*)&be[tid * 4];
  ushort4 o;
  o.x = f2b((v.x - mean) * rstd * gv.x + bv.x);
  o.y = f2b((v.y - mean) * rstd * gv.y + bv.y);
  o.z = f2b((v.z - mean) * rstd * gv.z + bv.z);
  o.w = f2b((v.w - mean) * rstd * gv.w + bv.w);
  *(ushort4*)&out[(size_t)row * DD + tid * 4] = o;
}

// ---------------- bf16 MFMA GEMM: C = A[M,K] @ BT[N,K]^T (+bias, epilogue) ----
// EPI: 0 = f32 out (+bias if nonnull)
//      1 = bf16 out (+bias)
//      2 = f32 out (+bias + res)   (residual add; out may alias res)
//      3 = bf16 out, exact GELU(acc+bias)
template <int EPI>
__global__ __launch_bounds__(256) void gemm_bt(const unsigned short* __restrict__ A,
                                               const unsigned short* __restrict__ BT,
                                               const float* __restrict__ bias,
                                               const float* __restrict__ res,
                                               void* __restrict__ outp,
                                               int M, int N, int K) {
  __shared__ __align__(16) unsigned short As[128 * 32];
  __shared__ __align__(16) unsigned short Bs[128 * 32];
  const int tid = threadIdx.x;
  const int lane = tid & 63;
  const int w = tid >> 6;
  const int n0 = blockIdx.x * 128, m0 = blockIdx.y * 128;
  const int wm = w & 1, wn = w >> 1;  // wave -> 64x64 quadrant
  f32x4 acc[4][4] = {};

  for (int k0 = 0; k0 < K; k0 += 32) {
    if (k0) __syncthreads();  // protect LDS from overwrite while prev iter reads
    // async staging: each wave stages 2x16 rows of A and B (16B/lane, linear LDS)
#pragma unroll
    for (int it = 0; it < 2; it++) {
      const int rt = w * 2 + it;          // row-tile 0..7
      const int rA = rt * 16 + (lane >> 2);
      const int ch = (lane & 3) * 8;
      gl_lds16(&A[(size_t)(m0 + rA) * K + k0 + ch], &As[rt * 512]);
      gl_lds16(&BT[(size_t)(n0 + rA) * K + k0 + ch], &Bs[rt * 512]);
    }
    __syncthreads();  // drains vmcnt(0) for global_load_lds
    bf16x8 af[4], bfr[4];
#pragma unroll
    for (int m = 0; m < 4; m++)
      af[m] = __builtin_bit_cast(
          bf16x8, *(const s16x8*)&As[(wm * 64 + m * 16 + (lane & 15)) * 32 + (lane >> 4) * 8]);
#pragma unroll
    for (int n = 0; n < 4; n++)
      bfr[n] = __builtin_bit_cast(
          bf16x8, *(const s16x8*)&Bs[(wn * 64 + n * 16 + (lane & 15)) * 32 + (lane >> 4) * 8]);
#pragma unroll
    for (int m = 0; m < 4; m++)
#pragma unroll
      for (int n = 0; n < 4; n++)
        acc[m][n] = __builtin_amdgcn_mfma_f32_16x16x32_bf16(af[m], bfr[n], acc[m][n], 0, 0, 0);
  }

  const int r0 = (lane >> 4) * 4;
  const int cc = lane & 15;
#pragma unroll
  for (int m = 0; m < 4; m++) {
#pragma unroll
    for (int n = 0; n < 4; n++) {
#pragma unroll
      for (int r = 0; r < 4; r++) {
        const int row = m0 + wm * 64 + m * 16 + r0 + r;
        const int col = n0 + wn * 64 + n * 16 + cc;
        const size_t idx = (size_t)row * N + col;
        float val = acc[m][n][r] + (bias ? bias[col] : 0.0f);
        if (EPI == 0) {
          ((float*)outp)[idx] = val;
        } else if (EPI == 1) {
          ((unsigned short*)outp)[idx] = f2b(val);
        } else if (EPI == 2) {
          ((float*)outp)[idx] = val + res[idx];
        } else {
          const float gv = 0.5f * val * (1.0f + erff(val * 0.70710678118654752f));
          ((unsigned short*)outp)[idx] = f2b(gv);
        }
      }
    }
  }
}

// ---------------- MFMA sparse attention ----------------
// One wave = 16-query tile of one (b,h). Key tiles of 32:
//   tile 0: gathered global-stride keys j=256*e with j < ka0 (<=8 slots)
//   tiles 1..nl: local window [ka0, i0+15], ka0 = align32(max(0, i0-128))
// Two-pass softmax, scores held in registers (<=6 tiles x 8 f32/lane).
#define QT 16
#define KT 32
#define NTMAX 6
#define KP 72   // padded K/V tile row (shorts)
#define PP 40   // padded P row (shorts)

__global__ __launch_bounds__(256) void attn_mfma(const unsigned short* __restrict__ qg,
                                                 const unsigned short* __restrict__ kg,
                                                 const unsigned short* __restrict__ vg,
                                                 unsigned short* __restrict__ outg) {
  __shared__ __align__(16) unsigned short kvs[4][KT * KP];
  __shared__ __align__(16) unsigned short pls[4][QT * PP];
  const int tid = threadIdx.x;
  const int wid = tid >> 6, lane = tid & 63;
  const int qgrp = blockIdx.x & 31;         // 64-query group within (b,h)
  const int bh = blockIdx.x >> 5;
  const int h = bh & (HH - 1), b = bh >> 4;
  const size_t base = (size_t)b * TT * DD + (size_t)h * HD;
  const int i0 = qgrp * 64 + wid * 16;
  const int g = lane >> 4;                  // 0..3
  const int c = lane & 15;

  // block-uniform loop bounds (from the largest i0 in the block)
  const int i0b = qgrp * 64 + 48;
  const int ka0b = (i0b > 128) ? ((i0b - 128) & ~31) : 0;
  const int nlb = ((i0b + 16 - ka0b) + 31) >> 5;   // 1..5
  const int neb = (ka0b + 255) >> 8;
  // per-wave geometry
  const int ka0 = (i0 > 128) ? ((i0 - 128) & ~31) : 0;
  const int ne = (ka0 + 255) >> 8;                 // globals strictly below ka0

  // Q fragment: row c, d-chunks at g*8 and 32+g*8
  const s16x8 qf0 = *(const s16x8*)&qg[base + (size_t)(i0 + c) * DD + g * 8];
  const s16x8 qf1 = *(const s16x8*)&qg[base + (size_t)(i0 + c) * DD + 32 + g * 8];

  f32x4 sc[NTMAX][2];
  float smax[4] = {-1e30f, -1e30f, -1e30f, -1e30f};

  // ---------------- pass 1: masked scaled scores ----------------
#pragma unroll
  for (int t = 0; t < NTMAX; t++) {
    if (t > nlb) continue;                 // block-uniform
    const bool isg = (t == 0);
    if (isg && neb == 0) continue;         // block-uniform
    const int kt0 = ka0 + (t - 1) * 32;
    // stage K tile (32 rows x 64 d) into padded LDS
#pragma unroll
    for (int it = 0; it < 4; it++) {
      const int row = it * 8 + (lane >> 3);
      const int ch = lane & 7;
      const int j = isg ? ((row < ne) ? row * STRIDE_G : 0) : (kt0 + row);
      *(s16x8*)&kvs[wid][row * KP + ch * 8] =
          *(const s16x8*)&kg[base + (size_t)j * DD + ch * 8];
    }
    __syncthreads();
#pragma unroll
    for (int half = 0; half < 2; half++) {
      const int key = half * 16 + c;
      const bf16x8 kb0 = __builtin_bit_cast(bf16x8, *(const s16x8*)&kvs[wid][key * KP + g * 8]);
      const bf16x8 kb1 = __builtin_bit_cast(bf16x8, *(const s16x8*)&kvs[wid][key * KP + 32 + g * 8]);
      f32x4 a = {};
      a = __builtin_amdgcn_mfma_f32_16x16x32_bf16(__builtin_bit_cast(bf16x8, qf0), kb0, a, 0, 0, 0);
      a = __builtin_amdgcn_mfma_f32_16x16x32_bf16(__builtin_bit_cast(bf16x8, qf1), kb1, a, 0, 0, 0);
#pragma unroll
      for (int r = 0; r < 4; r++) {
        const int i = i0 + g * 4 + r;
        bool ok;
        if (isg) {
          ok = (key < ne);
        } else {
          const int j = kt0 + key;
          ok = (j <= i) && (((i - j) <= LOCAL_W) || ((j & (STRIDE_G - 1)) == 0));
        }
        const float s = ok ? a[r] * 0.125f : -1e30f;
        sc[t][half][r] = s;
        smax[r] = fmaxf(smax[r], s);
      }
    }
    __syncthreads();
  }
#pragma unroll
  for (int r = 0; r < 4; r++)
#pragma unroll
    for (int off = 8; off; off >>= 1)
      smax[r] = fmaxf(smax[r], __shfl_xor(smax[r], off));

  // ---------------- pass 2: P = exp(s-m), O += P @ V ----------------
  f32x4 o[4] = {};      // o[d0][r]
  float lsum[4] = {0.f, 0.f, 0.f, 0.f};
#pragma unroll
  for (int t = 0; t < NTMAX; t++) {
    if (t > nlb) continue;
    const bool isg = (t == 0);
    if (isg && neb == 0) continue;
    const int kt0 = ka0 + (t - 1) * 32;
    // stage V tile
#pragma unroll
    for (int it = 0; it < 4; it++) {
      const int row = it * 8 + (lane >> 3);
      const int ch = lane & 7;
      const int j = isg ? ((row < ne) ? row * STRIDE_G : 0) : (kt0 + row);
      *(s16x8*)&kvs[wid][row * KP + ch * 8] =
          *(const s16x8*)&vg[base + (size_t)j * DD + ch * 8];
    }
    // P -> LDS (C-layout scatter: row g*4+r, col half*16+c)
#pragma unroll
    for (int half = 0; half < 2; half++)
#pragma unroll
      for (int r = 0; r < 4; r++) {
        const float p = __expf(sc[t][half][r] - smax[r]);
        lsum[r] += p;
        pls[wid][(g * 4 + r) * PP + half * 16 + c] = f2b(p);
      }
    __syncthreads();
    // A-fragment of P: row c, keys g*8..g*8+7
    const bf16x8 pa = __builtin_bit_cast(bf16x8, *(const s16x8*)&pls[wid][c * PP + g * 8]);
#pragma unroll
    for (int d0 = 0; d0 < 4; d0++) {
      s16x8 bv;
#pragma unroll
      for (int e = 0; e < 8; e++)
        bv[e] = (short)kvs[wid][(g * 8 + e) * KP + d0 * 16 + c];
      o[d0] = __builtin_amdgcn_mfma_f32_16x16x32_bf16(pa, __builtin_bit_cast(bf16x8, bv), o[d0], 0, 0, 0);
    }
    __syncthreads();
  }
#pragma unroll
  for (int r = 0; r < 4; r++)
#pragma unroll
    for (int off = 8; off; off >>= 1)
      lsum[r] += __shfl_xor(lsum[r], off);
#pragma unroll
  for (int d0 = 0; d0 < 4; d0++)
#pragma unroll
    for (int r = 0; r < 4; r++)
      outg[base + (size_t)(i0 + g * 4 + r) * DD + d0 * 16 + c] = f2b(o[d0][r] / lsum[r]);
}

// ---------------- host ----------------
extern "C" void kernel_launch(void* const* d_in, const int* in_sizes, int n_in,
                              void* d_out, int out_size, void* d_ws, size_t ws_size,
                              hipStream_t stream) {
  const int* x = (const int*)d_in[0];
  const float* embed = (const float*)d_in[1];
  const float* pos = (const float*)d_in[2];
  const float* Wq = (const float*)d_in[3];
  const float* bq = (const float*)d_in[4];
  const float* Wk = (const float*)d_in[5];
  const float* bk = (const float*)d_in[6];
  const float* Wv = (const float*)d_in[7];
  const float* bv = (const float*)d_in[8];
  const float* Wo = (const float*)d_in[9];
  const float* bo = (const float*)d_in[10];
  const float* g1 = (const float*)d_in[11];
  const float* be1 = (const float*)d_in[12];
  const float* W1 = (const float*)d_in[13];
  const float* bf1 = (const float*)d_in[14];
  const float* W2 = (const float*)d_in[15];
  const float* bf2 = (const float*)d_in[16];
  const float* g2 = (const float*)d_in[17];
  const float* be2 = (const float*)d_in[18];
  const float* gf = (const float*)d_in[19];
  const float* bef = (const float*)d_in[20];
  const float* Whead = (const float*)d_in[21];

  char* ws = (char*)d_ws;
  size_t off = 0;
  auto alloc = [&](size_t bytes) -> void* {
    void* p = ws + off;
    off += (bytes + 255) & ~(size_t)255;
    return p;
  };
  unsigned short* WqT = (unsigned short*)alloc((size_t)2 * DD * DD * 2);
  unsigned short* WkT = (unsigned short*)alloc((size_t)2 * DD * DD * 2);
  unsigned short* WvT = (unsigned short*)alloc((size_t)2 * DD * DD * 2);
  unsigned short* WoT = (unsigned short*)alloc((size_t)2 * DD * DD * 2);
  unsigned short* W1T = (unsigned short*)alloc((size_t)2 * DD * FF * 2);
  unsigned short* W2T = (unsigned short*)alloc((size_t)2 * DD * FF * 2);
  unsigned short* WheadT = (unsigned short*)alloc((size_t)DD * VV * 2);
  float* h = (float*)alloc((size_t)MM * DD * 4);
  unsigned short* hn = (unsigned short*)alloc((size_t)MM * DD * 2);
  unsigned short* qb = (unsigned short*)alloc((size_t)MM * DD * 2);
  unsigned short* kb = (unsigned short*)alloc((size_t)MM * DD * 2);
  unsigned short* vb = (unsigned short*)alloc((size_t)MM * DD * 2);
  unsigned short* attnb = (unsigned short*)alloc((size_t)MM * DD * 2);
  unsigned short* mid = (unsigned short*)alloc((size_t)MM * FF * 2);
  (void)ws_size;

  const dim3 tb(32, 8);
  for (int l = 0; l < 2; l++) {
    const size_t wo = (size_t)l * DD * DD;
    const size_t wf = (size_t)l * DD * FF;
    transpose_k<<<dim3(DD / 32, DD / 32), tb, 0, stream>>>(Wq + wo, WqT + wo, DD, DD);
    transpose_k<<<dim3(DD / 32, DD / 32), tb, 0, stream>>>(Wk + wo, WkT + wo, DD, DD);
    transpose_k<<<dim3(DD / 32, DD / 32), tb, 0, stream>>>(Wv + wo, WvT + wo, DD, DD);
    transpose_k<<<dim3(DD / 32, DD / 32), tb, 0, stream>>>(Wo + wo, WoT + wo, DD, DD);
    transpose_k<<<dim3(FF / 32, DD / 32), tb, 0, stream>>>(W1 + wf, W1T + wf, DD, FF);
    transpose_k<<<dim3(DD / 32, FF / 32), tb, 0, stream>>>(W2 + wf, W2T + wf, FF, DD);
  }
  transpose_k<<<dim3(VV / 32, DD / 32), tb, 0, stream>>>(Whead, WheadT, DD, VV);

  embed_kernel<<<MM, 256, 0, stream>>>(x, embed, pos, h);

  const dim3 gq(DD / 128, MM / 128);
  for (int l = 0; l < 2; l++) {
    const size_t wo = (size_t)l * DD * DD;
    const size_t wf = (size_t)l * DD * FF;
    ln_kernel<<<MM, 256, 0, stream>>>(h, g1 + l * DD, be1 + l * DD, hn);
    gemm_bt<1><<<gq, 256, 0, stream>>>(hn, WqT + wo, bq + l * DD, nullptr, qb, MM, DD, DD);
    gemm_bt<1><<<gq, 256, 0, stream>>>(hn, WkT + wo, bk + l * DD, nullptr, kb, MM, DD, DD);
    gemm_bt<1><<<gq, 256, 0, stream>>>(hn, WvT + wo, bv + l * DD, nullptr, vb, MM, DD, DD);
    attn_mfma<<<BB * HH * (TT / 64), 256, 0, stream>>>(qb, kb, vb, attnb);
    gemm_bt<2><<<gq, 256, 0, stream>>>(attnb, WoT + wo, bo + l * DD, h, h, MM, DD, DD);
    ln_kernel<<<MM, 256, 0, stream>>>(h, g2 + l * DD, be2 + l * DD, hn);
    gemm_bt<3><<<dim3(FF / 128, MM / 128), 256, 0, stream>>>(hn, W1T + wf, bf1 + l * FF,
                                                             nullptr, mid, MM, FF, DD);
    gemm_bt<2><<<gq, 256, 0, stream>>>(mid, W2T + wf, bf2 + l * DD, h, h, MM, DD, FF);
  }
  ln_kernel<<<MM, 256, 0, stream>>>(h, gf, bef, hn);
  gemm_bt<0><<<dim3(VV / 128, MM / 128), 256, 0, stream>>>(hn, WheadT, nullptr, nullptr,
                                                           d_out, MM, VV, DD);
}

// Round 3
// 616.606 us; speedup vs baseline: 2.0039x; 1.2207x over previous
//
#include <hip/hip_runtime.h>
#include <hip/hip_bf16.h>

// ---------------- problem constants ----------------
#define BB 2
#define TT 2048
#define DD 1024
#define FF 4096
#define VV 256
#define HH 16
#define HD 64
#define MM (BB * TT)      // 4096 rows
#define LOCAL_W 128
#define STRIDE_G 256

typedef short s16x8 __attribute__((ext_vector_type(8)));
typedef __bf16 bf16x8 __attribute__((ext_vector_type(8)));
typedef float f32x4 __attribute__((ext_vector_type(4)));

__device__ __forceinline__ float b2f(unsigned short u) {
  return __builtin_bit_cast(float, (unsigned int)u << 16);
}
__device__ __forceinline__ unsigned short f2b(float f) {
  __hip_bfloat16 h = __float2bfloat16(f);  // RNE
  return __builtin_bit_cast(unsigned short, h);
}
// async global->LDS, 16B per lane; LDS dest = wave-uniform base + lane*16
__device__ __forceinline__ void gl_lds16(const unsigned short* g, unsigned short* l) {
  __builtin_amdgcn_global_load_lds(
      (const __attribute__((address_space(1))) void*)g,
      (__attribute__((address_space(3))) void*)l, 16, 0, 0);
}

// ---------------- weight transpose f32[K][N] -> bf16[N][K] ----------------
__global__ __launch_bounds__(256) void transpose_k(const float* __restrict__ W,
                                                   unsigned short* __restrict__ WT,
                                                   int K, int N) {
  __shared__ float t[32][33];
  const int n0 = blockIdx.x * 32, k0 = blockIdx.y * 32;
  const int tx = threadIdx.x, ty = threadIdx.y;  // (32, 8)
  for (int r = ty; r < 32; r += 8) t[r][tx] = W[(size_t)(k0 + r) * N + n0 + tx];
  __syncthreads();
  for (int r = ty; r < 32; r += 8)
    WT[(size_t)(n0 + r) * K + k0 + tx] = f2b(t[tx][r]);
}

// ---------------- embedding + positional ----------------
__global__ __launch_bounds__(256) void embed_kernel(const int* __restrict__ x,
                                                    const float* __restrict__ emb,
                                                    const float* __restrict__ pos,
                                                    float* __restrict__ h) {
  const int row = blockIdx.x;
  const int c = threadIdx.x * 4;
  const int tok = x[row];
  const int t = row & (TT - 1);
  float4 e = *(const float4*)&emb[(size_t)tok * DD + c];
  float4 p = *(const float4*)&pos[(size_t)t * DD + c];
  e.x += p.x; e.y += p.y; e.z += p.z; e.w += p.w;
  *(float4*)&h[(size_t)row * DD + c] = e;
}

// ---------------- layernorm f32 -> bf16 ----------------
__global__ __launch_bounds__(256) void ln_kernel(const float* __restrict__ x,
                                                 const float* __restrict__ g,
                                                 const float* __restrict__ be,
                                                 unsigned short* __restrict__ out) {
  const int row = blockIdx.x;
  const int tid = threadIdx.x;
  const float4 v = *(const float4*)&x[(size_t)row * DD + tid * 4];
  float s = v.x + v.y + v.z + v.w;
  float sq = v.x * v.x + v.y * v.y + v.z * v.z + v.w * v.w;
#pragma unroll
  for (int off = 32; off; off >>= 1) {
    s += __shfl_xor(s, off);
    sq += __shfl_xor(sq, off);
  }
  __shared__ float ss[4], ssq[4];
  const int w = tid >> 6, lane = tid & 63;
  if (lane == 0) { ss[w] = s; ssq[w] = sq; }
  __syncthreads();
  s = ss[0] + ss[1] + ss[2] + ss[3];
  sq = ssq[0] + ssq[1] + ssq[2] + ssq[3];
  const float mean = s * (1.0f / DD);
  const float var = sq * (1.0f / DD) - mean * mean;
  const float rstd = rsqrtf(var + 1e-5f);
  const float4 gv = *(const float4*)&g[tid * 4];
  const float4 bv = *(const float4*)&be[tid * 4];
  ushort4 o;
  o.x = f2b((v.x - mean) * rstd * gv.x + bv.x);
  o.y = f2b((v.y - mean) * rstd * gv.y + bv.y);
  o.z = f2b((v.z - mean) * rstd * gv.z + bv.z);
  o.w = f2b((v.w - mean) * rstd * gv.w + bv.w);
  *(ushort4*)&out[(size_t)row * DD + tid * 4] = o;
}

// ---------------- bf16 MFMA GEMM: C = A[M,K] @ BT[N,K]^T (+bias, epilogue) ----
// 512 threads = 8 waves (2M x 4N), 128x128 tile, BK=32, 2-phase double-buffered
// global_load_lds pipeline, XCD-swizzled flattened grid (nwg % 8 == 0).
// EPI: 0 = f32 out (+bias if nonnull)
//      1 = bf16 out (+bias)
//      2 = f32 out (+bias + res)   (residual add; out may alias res)
//      3 = bf16 out, exact GELU(acc+bias)
template <int EPI>
__global__ __launch_bounds__(512) void gemm_bt(const unsigned short* __restrict__ A,
                                               const unsigned short* __restrict__ BT,
                                               const float* __restrict__ bias,
                                               const float* __restrict__ res,
                                               void* __restrict__ outp,
                                               int M, int N, int K, int nbx) {
  __shared__ __align__(16) unsigned short As[2][128 * 32];
  __shared__ __align__(16) unsigned short Bs[2][128 * 32];
  const int tid = threadIdx.x;
  const int lane = tid & 63;
  const int w = tid >> 6;  // 0..7
  // T1: bijective XCD swizzle (nwg multiple of 8)
  const int nwg = gridDim.x;
  const int orig = blockIdx.x;
  const int wg = (orig & 7) * (nwg >> 3) + (orig >> 3);
  const int n0 = (wg % nbx) * 128, m0 = (wg / nbx) * 128;
  const int wm = w >> 2, wn = w & 3;  // wave tile: 64 rows x 32 cols
  f32x4 acc[4][2] = {};

  // staging: wave w stages rows [w*16, w*16+16) of both tiles (1 KiB each)
  const int srow = w * 16 + (lane >> 2);
  const int sch = (lane & 3) * 8;
  const unsigned short* aP = &A[(size_t)(m0 + srow) * K + sch];
  const unsigned short* bP = &BT[(size_t)(n0 + srow) * K + sch];

  const int nt = K >> 5;
  // prologue
  gl_lds16(aP, &As[0][w * 512]);
  gl_lds16(bP, &Bs[0][w * 512]);
  __syncthreads();

  for (int t = 0; t < nt; ++t) {
    if (t + 1 < nt) {  // prefetch next K-tile into other buffer
      const int k1 = (t + 1) << 5;
      gl_lds16(aP + k1, &As[(t + 1) & 1][w * 512]);
      gl_lds16(bP + k1, &Bs[(t + 1) & 1][w * 512]);
    }
    const int cur = t & 1;
    bf16x8 af[4], bfr[2];
#pragma unroll
    for (int m = 0; m < 4; m++)
      af[m] = __builtin_bit_cast(
          bf16x8,
          *(const s16x8*)&As[cur][(wm * 64 + m * 16 + (lane & 15)) * 32 + (lane >> 4) * 8]);
#pragma unroll
    for (int n = 0; n < 2; n++)
      bfr[n] = __builtin_bit_cast(
          bf16x8,
          *(const s16x8*)&Bs[cur][(wn * 32 + n * 16 + (lane & 15)) * 32 + (lane >> 4) * 8]);
#pragma unroll
    for (int m = 0; m < 4; m++)
#pragma unroll
      for (int n = 0; n < 2; n++)
        acc[m][n] = __builtin_amdgcn_mfma_f32_16x16x32_bf16(af[m], bfr[n], acc[m][n], 0, 0, 0);
    __syncthreads();  // drains vmcnt(0) (prefetch) + guards buffer reuse
  }

  const int r0 = (lane >> 4) * 4;
  const int cc = lane & 15;
#pragma unroll
  for (int m = 0; m < 4; m++) {
#pragma unroll
    for (int n = 0; n < 2; n++) {
#pragma unroll
      for (int r = 0; r < 4; r++) {
        const int row = m0 + wm * 64 + m * 16 + r0 + r;
        const int col = n0 + wn * 32 + n * 16 + cc;
        const size_t idx = (size_t)row * N + col;
        float val = acc[m][n][r] + (bias ? bias[col] : 0.0f);
        if (EPI == 0) {
          ((float*)outp)[idx] = val;
        } else if (EPI == 1) {
          ((unsigned short*)outp)[idx] = f2b(val);
        } else if (EPI == 2) {
          ((float*)outp)[idx] = val + res[idx];
        } else {
          const float gv = 0.5f * val * (1.0f + erff(val * 0.70710678118654752f));
          ((unsigned short*)outp)[idx] = f2b(gv);
        }
      }
    }
  }
}

// ---------------- MFMA sparse attention ----------------
// One wave = 16-query tile of one (b,h). Key tiles of 32:
//   tile 0: gathered global-stride keys j=256*e with j < ka0 (<=8 slots)
//   tiles 1..nl: local window [ka0, i0+15], ka0 = align32(max(0, i0-128))
// Two-pass softmax, scores held in registers (<=6 tiles x 8 f32/lane).
#define QT 16
#define KT 32
#define NTMAX 6
#define KP 72   // padded K/V tile row (shorts)
#define PP 40   // padded P row (shorts)

__global__ __launch_bounds__(256) void attn_mfma(const unsigned short* __restrict__ qg,
                                                 const unsigned short* __restrict__ kg,
                                                 const unsigned short* __restrict__ vg,
                                                 unsigned short* __restrict__ outg) {
  __shared__ __align__(16) unsigned short kvs[4][KT * KP];
  __shared__ __align__(16) unsigned short pls[4][QT * PP];
  const int tid = threadIdx.x;
  const int wid = tid >> 6, lane = tid & 63;
  const int qgrp = blockIdx.x & 31;         // 64-query group within (b,h)
  const int bh = blockIdx.x >> 5;
  const int h = bh & (HH - 1), b = bh >> 4;
  const size_t base = (size_t)b * TT * DD + (size_t)h * HD;
  const int i0 = qgrp * 64 + wid * 16;
  const int g = lane >> 4;                  // 0..3
  const int c = lane & 15;

  // block-uniform loop bounds (from the largest i0 in the block)
  const int i0b = qgrp * 64 + 48;
  const int ka0b = (i0b > 128) ? ((i0b - 128) & ~31) : 0;
  const int nlb = ((i0b + 16 - ka0b) + 31) >> 5;   // 1..5
  const int neb = (ka0b + 255) >> 8;
  // per-wave geometry
  const int ka0 = (i0 > 128) ? ((i0 - 128) & ~31) : 0;
  const int ne = (ka0 + 255) >> 8;                 // globals strictly below ka0

  // Q fragment: row c, d-chunks at g*8 and 32+g*8
  const s16x8 qf0 = *(const s16x8*)&qg[base + (size_t)(i0 + c) * DD + g * 8];
  const s16x8 qf1 = *(const s16x8*)&qg[base + (size_t)(i0 + c) * DD + 32 + g * 8];

  f32x4 sc[NTMAX][2];
  float smax[4] = {-1e30f, -1e30f, -1e30f, -1e30f};

  // ---------------- pass 1: masked scaled scores ----------------
#pragma unroll
  for (int t = 0; t < NTMAX; t++) {
    if (t > nlb) continue;                 // block-uniform
    const bool isg = (t == 0);
    if (isg && neb == 0) continue;         // block-uniform
    const int kt0 = ka0 + (t - 1) * 32;
    // stage K tile (32 rows x 64 d) into padded LDS
#pragma unroll
    for (int it = 0; it < 4; it++) {
      const int row = it * 8 + (lane >> 3);
      const int ch = lane & 7;
      const int j = isg ? ((row < ne) ? row * STRIDE_G : 0) : (kt0 + row);
      *(s16x8*)&kvs[wid][row * KP + ch * 8] =
          *(const s16x8*)&kg[base + (size_t)j * DD + ch * 8];
    }
    __syncthreads();
#pragma unroll
    for (int half = 0; half < 2; half++) {
      const int key = half * 16 + c;
      const bf16x8 kb0 = __builtin_bit_cast(bf16x8, *(const s16x8*)&kvs[wid][key * KP + g * 8]);
      const bf16x8 kb1 = __builtin_bit_cast(bf16x8, *(const s16x8*)&kvs[wid][key * KP + 32 + g * 8]);
      f32x4 a = {};
      a = __builtin_amdgcn_mfma_f32_16x16x32_bf16(__builtin_bit_cast(bf16x8, qf0), kb0, a, 0, 0, 0);
      a = __builtin_amdgcn_mfma_f32_16x16x32_bf16(__builtin_bit_cast(bf16x8, qf1), kb1, a, 0, 0, 0);
#pragma unroll
      for (int r = 0; r < 4; r++) {
        const int i = i0 + g * 4 + r;
        bool ok;
        if (isg) {
          ok = (key < ne);
        } else {
          const int j = kt0 + key;
          ok = (j <= i) && (((i - j) <= LOCAL_W) || ((j & (STRIDE_G - 1)) == 0));
        }
        const float s = ok ? a[r] * 0.125f : -1e30f;
        sc[t][half][r] = s;
        smax[r] = fmaxf(smax[r], s);
      }
    }
    __syncthreads();
  }
#pragma unroll
  for (int r = 0; r < 4; r++)
#pragma unroll
    for (int off = 8; off; off >>= 1)
      smax[r] = fmaxf(smax[r], __shfl_xor(smax[r], off));

  // ---------------- pass 2: P = exp(s-m), O += P @ V ----------------
  f32x4 o[4] = {};      // o[d0][r]
  float lsum[4] = {0.f, 0.f, 0.f, 0.f};
#pragma unroll
  for (int t = 0; t < NTMAX; t++) {
    if (t > nlb) continue;
    const bool isg = (t == 0);
    if (isg && neb == 0) continue;
    const int kt0 = ka0 + (t - 1) * 32;
    // stage V tile
#pragma unroll
    for (int it = 0; it < 4; it++) {
      const int row = it * 8 + (lane >> 3);
      const int ch = lane & 7;
      const int j = isg ? ((row < ne) ? row * STRIDE_G : 0) : (kt0 + row);
      *(s16x8*)&kvs[wid][row * KP + ch * 8] =
          *(const s16x8*)&vg[base + (size_t)j * DD + ch * 8];
    }
    // P -> LDS (C-layout scatter: row g*4+r, col half*16+c)
#pragma unroll
    for (int half = 0; half < 2; half++)
#pragma unroll
      for (int r = 0; r < 4; r++) {
        const float p = __expf(sc[t][half][r] - smax[r]);
        lsum[r] += p;
        pls[wid][(g * 4 + r) * PP + half * 16 + c] = f2b(p);
      }
    __syncthreads();
    // A-fragment of P: row c, keys g*8..g*8+7
    const bf16x8 pa = __builtin_bit_cast(bf16x8, *(const s16x8*)&pls[wid][c * PP + g * 8]);
#pragma unroll
    for (int d0 = 0; d0 < 4; d0++) {
      s16x8 bv;
#pragma unroll
      for (int e = 0; e < 8; e++)
        bv[e] = (short)kvs[wid][(g * 8 + e) * KP + d0 * 16 + c];
      o[d0] = __builtin_amdgcn_mfma_f32_16x16x32_bf16(pa, __builtin_bit_cast(bf16x8, bv), o[d0], 0, 0, 0);
    }
    __syncthreads();
  }
#pragma unroll
  for (int r = 0; r < 4; r++)
#pragma unroll
    for (int off = 8; off; off >>= 1)
      lsum[r] += __shfl_xor(lsum[r], off);
#pragma unroll
  for (int d0 = 0; d0 < 4; d0++)
#pragma unroll
    for (int r = 0; r < 4; r++)
      outg[base + (size_t)(i0 + g * 4 + r) * DD + d0 * 16 + c] = f2b(o[d0][r] / lsum[r]);
}

// ---------------- host ----------------
extern "C" void kernel_launch(void* const* d_in, const int* in_sizes, int n_in,
                              void* d_out, int out_size, void* d_ws, size_t ws_size,
                              hipStream_t stream) {
  const int* x = (const int*)d_in[0];
  const float* embed = (const float*)d_in[1];
  const float* pos = (const float*)d_in[2];
  const float* Wq = (const float*)d_in[3];
  const float* bq = (const float*)d_in[4];
  const float* Wk = (const float*)d_in[5];
  const float* bk = (const float*)d_in[6];
  const float* Wv = (const float*)d_in[7];
  const float* bv = (const float*)d_in[8];
  const float* Wo = (const float*)d_in[9];
  const float* bo = (const float*)d_in[10];
  const float* g1 = (const float*)d_in[11];
  const float* be1 = (const float*)d_in[12];
  const float* W1 = (const float*)d_in[13];
  const float* bf1 = (const float*)d_in[14];
  const float* W2 = (const float*)d_in[15];
  const float* bf2 = (const float*)d_in[16];
  const float* g2 = (const float*)d_in[17];
  const float* be2 = (const float*)d_in[18];
  const float* gf = (const float*)d_in[19];
  const float* bef = (const float*)d_in[20];
  const float* Whead = (const float*)d_in[21];

  char* ws = (char*)d_ws;
  size_t off = 0;
  auto alloc = [&](size_t bytes) -> void* {
    void* p = ws + off;
    off += (bytes + 255) & ~(size_t)255;
    return p;
  };
  unsigned short* WqT = (unsigned short*)alloc((size_t)2 * DD * DD * 2);
  unsigned short* WkT = (unsigned short*)alloc((size_t)2 * DD * DD * 2);
  unsigned short* WvT = (unsigned short*)alloc((size_t)2 * DD * DD * 2);
  unsigned short* WoT = (unsigned short*)alloc((size_t)2 * DD * DD * 2);
  unsigned short* W1T = (unsigned short*)alloc((size_t)2 * DD * FF * 2);
  unsigned short* W2T = (unsigned short*)alloc((size_t)2 * DD * FF * 2);
  unsigned short* WheadT = (unsigned short*)alloc((size_t)DD * VV * 2);
  float* h = (float*)alloc((size_t)MM * DD * 4);
  unsigned short* hn = (unsigned short*)alloc((size_t)MM * DD * 2);
  unsigned short* qb = (unsigned short*)alloc((size_t)MM * DD * 2);
  unsigned short* kb = (unsigned short*)alloc((size_t)MM * DD * 2);
  unsigned short* vb = (unsigned short*)alloc((size_t)MM * DD * 2);
  unsigned short* attnb = (unsigned short*)alloc((size_t)MM * DD * 2);
  unsigned short* mid = (unsigned short*)alloc((size_t)MM * FF * 2);
  (void)ws_size;

  const dim3 tb(32, 8);
  for (int l = 0; l < 2; l++) {
    const size_t wo = (size_t)l * DD * DD;
    const size_t wf = (size_t)l * DD * FF;
    transpose_k<<<dim3(DD / 32, DD / 32), tb, 0, stream>>>(Wq + wo, WqT + wo, DD, DD);
    transpose_k<<<dim3(DD / 32, DD / 32), tb, 0, stream>>>(Wk + wo, WkT + wo, DD, DD);
    transpose_k<<<dim3(DD / 32, DD / 32), tb, 0, stream>>>(Wv + wo, WvT + wo, DD, DD);
    transpose_k<<<dim3(DD / 32, DD / 32), tb, 0, stream>>>(Wo + wo, WoT + wo, DD, DD);
    transpose_k<<<dim3(FF / 32, DD / 32), tb, 0, stream>>>(W1 + wf, W1T + wf, DD, FF);
    transpose_k<<<dim3(DD / 32, FF / 32), tb, 0, stream>>>(W2 + wf, W2T + wf, FF, DD);
  }
  transpose_k<<<dim3(VV / 32, DD / 32), tb, 0, stream>>>(Whead, WheadT, DD, VV);

  embed_kernel<<<MM, 256, 0, stream>>>(x, embed, pos, h);

  // flattened grids: nwg = (N/128) * (M/128), nbx = N/128
  const int gq = (DD / 128) * (MM / 128);
  for (int l = 0; l < 2; l++) {
    const size_t wo = (size_t)l * DD * DD;
    const size_t wf = (size_t)l * DD * FF;
    ln_kernel<<<MM, 256, 0, stream>>>(h, g1 + l * DD, be1 + l * DD, hn);
    gemm_bt<1><<<gq, 512, 0, stream>>>(hn, WqT + wo, bq + l * DD, nullptr, qb, MM, DD, DD, DD / 128);
    gemm_bt<1><<<gq, 512, 0, stream>>>(hn, WkT + wo, bk + l * DD, nullptr, kb, MM, DD, DD, DD / 128);
    gemm_bt<1><<<gq, 512, 0, stream>>>(hn, WvT + wo, bv + l * DD, nullptr, vb, MM, DD, DD, DD / 128);
    attn_mfma<<<BB * HH * (TT / 64), 256, 0, stream>>>(qb, kb, vb, attnb);
    gemm_bt<2><<<gq, 512, 0, stream>>>(attnb, WoT + wo, bo + l * DD, h, h, MM, DD, DD, DD / 128);
    ln_kernel<<<MM, 256, 0, stream>>>(h, g2 + l * DD, be2 + l * DD, hn);
    gemm_bt<3><<<(FF / 128) * (MM / 128), 512, 0, stream>>>(hn, W1T + wf, bf1 + l * FF,
                                                            nullptr, mid, MM, FF, DD, FF / 128);
    gemm_bt<2><<<gq, 512, 0, stream>>>(mid, W2T + wf, bf2 + l * DD, h, h, MM, DD, FF, DD / 128);
  }
  ln_kernel<<<MM, 256, 0, stream>>>(h, gf, bef, hn);
  gemm_bt<0><<<(VV / 128) * (MM / 128), 512, 0, stream>>>(hn, WheadT, nullptr, nullptr,
                                                          d_out, MM, VV, DD, VV / 128);
}

// Round 4
// 510.791 us; speedup vs baseline: 2.4191x; 1.2072x over previous
//
#include <hip/hip_runtime.h>
#include <hip/hip_bf16.h>

// ---------------- problem constants ----------------
#define BB 2
#define TT 2048
#define DD 1024
#define FF 4096
#define VV 256
#define HH 16
#define HD 64
#define MM (BB * TT)      // 4096 rows
#define LOCAL_W 128
#define STRIDE_G 256
#define QS 3072           // fused QKV row stride

typedef short s16x8 __attribute__((ext_vector_type(8)));
typedef __bf16 bf16x8 __attribute__((ext_vector_type(8)));
typedef float f32x4 __attribute__((ext_vector_type(4)));

__device__ __forceinline__ float b2f(unsigned short u) {
  return __builtin_bit_cast(float, (unsigned int)u << 16);
}
__device__ __forceinline__ unsigned short f2b(float f) {
  __hip_bfloat16 h = __float2bfloat16(f);  // RNE
  return __builtin_bit_cast(unsigned short, h);
}
// async global->LDS, 16B per lane; LDS dest = wave-uniform base + lane*16
__device__ __forceinline__ void gl_lds16(const unsigned short* g, unsigned short* l) {
  __builtin_amdgcn_global_load_lds(
      (const __attribute__((address_space(1))) void*)g,
      (__attribute__((address_space(3))) void*)l, 16, 0, 0);
}

// ---------------- weight transpose f32[K][N] -> bf16[N][K] ----------------
__global__ __launch_bounds__(256) void transpose_k(const float* __restrict__ W,
                                                   unsigned short* __restrict__ WT,
                                                   int K, int N) {
  __shared__ float t[32][33];
  const int n0 = blockIdx.x * 32, k0 = blockIdx.y * 32;
  const int tx = threadIdx.x, ty = threadIdx.y;  // (32, 8)
  for (int r = ty; r < 32; r += 8) t[r][tx] = W[(size_t)(k0 + r) * N + n0 + tx];
  __syncthreads();
  for (int r = ty; r < 32; r += 8)
    WT[(size_t)(n0 + r) * K + k0 + tx] = f2b(t[tx][r]);
}

// ---------------- concat QKV bias: bcat[l][3072] ----------------
__global__ __launch_bounds__(256) void concat_bias(const float* __restrict__ bq,
                                                   const float* __restrict__ bk,
                                                   const float* __restrict__ bv,
                                                   float* __restrict__ bcat) {
  const int i = blockIdx.x * 256 + threadIdx.x;  // 6144 total
  const int l = i / QS, j = i - l * QS;
  float v;
  if (j < DD) v = bq[l * DD + j];
  else if (j < 2 * DD) v = bk[l * DD + j - DD];
  else v = bv[l * DD + j - 2 * DD];
  bcat[i] = v;
}

// ---------------- embedding + positional ----------------
__global__ __launch_bounds__(256) void embed_kernel(const int* __restrict__ x,
                                                    const float* __restrict__ emb,
                                                    const float* __restrict__ pos,
                                                    float* __restrict__ h) {
  const int row = blockIdx.x;
  const int c = threadIdx.x * 4;
  const int tok = x[row];
  const int t = row & (TT - 1);
  float4 e = *(const float4*)&emb[(size_t)tok * DD + c];
  float4 p = *(const float4*)&pos[(size_t)t * DD + c];
  e.x += p.x; e.y += p.y; e.z += p.z; e.w += p.w;
  *(float4*)&h[(size_t)row * DD + c] = e;
}

// ---------------- layernorm f32 -> bf16 ----------------
__global__ __launch_bounds__(256) void ln_kernel(const float* __restrict__ x,
                                                 const float* __restrict__ g,
                                                 const float* __restrict__ be,
                                                 unsigned short* __restrict__ out) {
  const int row = blockIdx.x;
  const int tid = threadIdx.x;
  const float4 v = *(const float4*)&x[(size_t)row * DD + tid * 4];
  float s = v.x + v.y + v.z + v.w;
  float sq = v.x * v.x + v.y * v.y + v.z * v.z + v.w * v.w;
#pragma unroll
  for (int off = 32; off; off >>= 1) {
    s += __shfl_xor(s, off);
    sq += __shfl_xor(sq, off);
  }
  __shared__ float ss[4], ssq[4];
  const int w = tid >> 6, lane = tid & 63;
  if (lane == 0) { ss[w] = s; ssq[w] = sq; }
  __syncthreads();
  s = ss[0] + ss[1] + ss[2] + ss[3];
  sq = ssq[0] + ssq[1] + ssq[2] + ssq[3];
  const float mean = s * (1.0f / DD);
  const float var = sq * (1.0f / DD) - mean * mean;
  const float rstd = rsqrtf(var + 1e-5f);
  const float4 gv = *(const float4*)&g[tid * 4];
  const float4 bv = *(const float4*)&be[tid * 4];
  ushort4 o;
  o.x = f2b((v.x - mean) * rstd * gv.x + bv.x);
  o.y = f2b((v.y - mean) * rstd * gv.y + bv.y);
  o.z = f2b((v.z - mean) * rstd * gv.z + bv.z);
  o.w = f2b((v.w - mean) * rstd * gv.w + bv.w);
  *(ushort4*)&out[(size_t)row * DD + tid * 4] = o;
}

// ---------------- bf16 MFMA GEMM: C = A[M,K] @ BT[N,K]^T (+bias, epilogue) ----
// 512 threads = 8 waves (2M x 4N), 128x128 tile, BK=32, 2-phase double-buffered
// global_load_lds pipeline, XCD-swizzled flattened grid (nwg % 8 == 0).
// EPI: 1 = bf16 out (+bias)
//      2 = f32 out (+bias + res)   (residual add; out may alias res)
//      3 = bf16 out, exact GELU(acc+bias)
template <int EPI>
__global__ __launch_bounds__(512) void gemm_bt(const unsigned short* __restrict__ A,
                                               const unsigned short* __restrict__ BT,
                                               const float* __restrict__ bias,
                                               const float* __restrict__ res,
                                               void* __restrict__ outp,
                                               int M, int N, int K, int nbx) {
  __shared__ __align__(16) unsigned short As[2][128 * 32];
  __shared__ __align__(16) unsigned short Bs[2][128 * 32];
  const int tid = threadIdx.x;
  const int lane = tid & 63;
  const int w = tid >> 6;  // 0..7
  const int nwg = gridDim.x;
  const int orig = blockIdx.x;
  const int wg = (orig & 7) * (nwg >> 3) + (orig >> 3);
  const int n0 = (wg % nbx) * 128, m0 = (wg / nbx) * 128;
  const int wm = w >> 2, wn = w & 3;  // wave tile: 64 rows x 32 cols
  f32x4 acc[4][2] = {};

  const int srow = w * 16 + (lane >> 2);
  const int sch = (lane & 3) * 8;
  const unsigned short* aP = &A[(size_t)(m0 + srow) * K + sch];
  const unsigned short* bP = &BT[(size_t)(n0 + srow) * K + sch];

  const int nt = K >> 5;
  gl_lds16(aP, &As[0][w * 512]);
  gl_lds16(bP, &Bs[0][w * 512]);
  __syncthreads();

  for (int t = 0; t < nt; ++t) {
    if (t + 1 < nt) {
      const int k1 = (t + 1) << 5;
      gl_lds16(aP + k1, &As[(t + 1) & 1][w * 512]);
      gl_lds16(bP + k1, &Bs[(t + 1) & 1][w * 512]);
    }
    const int cur = t & 1;
    bf16x8 af[4], bfr[2];
#pragma unroll
    for (int m = 0; m < 4; m++)
      af[m] = __builtin_bit_cast(
          bf16x8,
          *(const s16x8*)&As[cur][(wm * 64 + m * 16 + (lane & 15)) * 32 + (lane >> 4) * 8]);
#pragma unroll
    for (int n = 0; n < 2; n++)
      bfr[n] = __builtin_bit_cast(
          bf16x8,
          *(const s16x8*)&Bs[cur][(wn * 32 + n * 16 + (lane & 15)) * 32 + (lane >> 4) * 8]);
#pragma unroll
    for (int m = 0; m < 4; m++)
#pragma unroll
      for (int n = 0; n < 2; n++)
        acc[m][n] = __builtin_amdgcn_mfma_f32_16x16x32_bf16(af[m], bfr[n], acc[m][n], 0, 0, 0);
    __syncthreads();
  }

  const int r0 = (lane >> 4) * 4;
  const int cc = lane & 15;
#pragma unroll
  for (int m = 0; m < 4; m++) {
#pragma unroll
    for (int n = 0; n < 2; n++) {
#pragma unroll
      for (int r = 0; r < 4; r++) {
        const int row = m0 + wm * 64 + m * 16 + r0 + r;
        const int col = n0 + wn * 32 + n * 16 + cc;
        const size_t idx = (size_t)row * N + col;
        float val = acc[m][n][r] + (bias ? bias[col] : 0.0f);
        if (EPI == 1) {
          ((unsigned short*)outp)[idx] = f2b(val);
        } else if (EPI == 2) {
          ((float*)outp)[idx] = val + res[idx];
        } else {
          const float gv = 0.5f * val * (1.0f + erff(val * 0.70710678118654752f));
          ((unsigned short*)outp)[idx] = f2b(gv);
        }
      }
    }
  }
}

// ---------------- split-K GEMM: partial[ks] = A @ BT^T over K-slice ----------------
__global__ __launch_bounds__(512) void gemm_sk(const unsigned short* __restrict__ A,
                                               const unsigned short* __restrict__ BT,
                                               float* __restrict__ partial,
                                               int M, int N, int K, int nbx, int nwg2,
                                               int ksub) {
  __shared__ __align__(16) unsigned short As[2][128 * 32];
  __shared__ __align__(16) unsigned short Bs[2][128 * 32];
  const int tid = threadIdx.x;
  const int lane = tid & 63;
  const int w = tid >> 6;
  const int nwg = gridDim.x;
  const int orig = blockIdx.x;
  const int wg = (orig & 7) * (nwg >> 3) + (orig >> 3);
  const int ks = wg / nwg2;
  const int rem = wg - ks * nwg2;
  const int n0 = (rem % nbx) * 128, m0 = (rem / nbx) * 128;
  const int kb = ks * ksub;
  const int wm = w >> 2, wn = w & 3;
  f32x4 acc[4][2] = {};

  const int srow = w * 16 + (lane >> 2);
  const int sch = (lane & 3) * 8;
  const unsigned short* aP = &A[(size_t)(m0 + srow) * K + kb + sch];
  const unsigned short* bP = &BT[(size_t)(n0 + srow) * K + kb + sch];

  const int nt = ksub >> 5;
  gl_lds16(aP, &As[0][w * 512]);
  gl_lds16(bP, &Bs[0][w * 512]);
  __syncthreads();

  for (int t = 0; t < nt; ++t) {
    if (t + 1 < nt) {
      const int k1 = (t + 1) << 5;
      gl_lds16(aP + k1, &As[(t + 1) & 1][w * 512]);
      gl_lds16(bP + k1, &Bs[(t + 1) & 1][w * 512]);
    }
    const int cur = t & 1;
    bf16x8 af[4], bfr[2];
#pragma unroll
    for (int m = 0; m < 4; m++)
      af[m] = __builtin_bit_cast(
          bf16x8,
          *(const s16x8*)&As[cur][(wm * 64 + m * 16 + (lane & 15)) * 32 + (lane >> 4) * 8]);
#pragma unroll
    for (int n = 0; n < 2; n++)
      bfr[n] = __builtin_bit_cast(
          bf16x8,
          *(const s16x8*)&Bs[cur][(wn * 32 + n * 16 + (lane & 15)) * 32 + (lane >> 4) * 8]);
#pragma unroll
    for (int m = 0; m < 4; m++)
#pragma unroll
      for (int n = 0; n < 2; n++)
        acc[m][n] = __builtin_amdgcn_mfma_f32_16x16x32_bf16(af[m], bfr[n], acc[m][n], 0, 0, 0);
    __syncthreads();
  }

  float* outP = partial + (size_t)ks * M * N;
  const int r0 = (lane >> 4) * 4;
  const int cc = lane & 15;
#pragma unroll
  for (int m = 0; m < 4; m++)
#pragma unroll
    for (int n = 0; n < 2; n++)
#pragma unroll
      for (int r = 0; r < 4; r++) {
        const int row = m0 + wm * 64 + m * 16 + r0 + r;
        const int col = n0 + wn * 32 + n * 16 + cc;
        outP[(size_t)row * N + col] = acc[m][n][r];
      }
}

// ---------------- reduce: dst = (RES? dst) + (BIAS? bias) + sum(parts) ----------------
template <int NP, bool BIAS, bool RES>
__global__ __launch_bounds__(256) void reduce_k(float* __restrict__ dst,
                                                const float* __restrict__ parts,
                                                const float* __restrict__ bias,
                                                int ncols, size_t total) {
  const size_t i = ((size_t)blockIdx.x * 256 + threadIdx.x) * 4;
  if (i >= total) return;
  f32x4 acc = {};
  if (RES) acc = *(const f32x4*)&dst[i];
  if (BIAS) {
    const int col = (int)(i % ncols);
    acc += *(const f32x4*)&bias[col];
  }
#pragma unroll
  for (int p = 0; p < NP; p++) acc += *(const f32x4*)&parts[(size_t)p * total + i];
  *(f32x4*)&dst[i] = acc;
}

// ---------------- MFMA sparse attention (fused-QKV input, stride QS) ----------------
#define QT 16
#define KT 32
#define NTMAX 6
#define KP 72   // padded K/V tile row (shorts)
#define PP 40   // padded P row (shorts)

__global__ __launch_bounds__(256) void attn_mfma(const unsigned short* __restrict__ qkv,
                                                 unsigned short* __restrict__ outg) {
  __shared__ __align__(16) unsigned short kvs[4][KT * KP];
  __shared__ __align__(16) unsigned short pls[4][QT * PP];
  const int tid = threadIdx.x;
  const int wid = tid >> 6, lane = tid & 63;
  const int qgrp = blockIdx.x & 31;         // 64-query group within (b,h)
  const int bh = blockIdx.x >> 5;
  const int h = bh & (HH - 1), b = bh >> 4;
  const size_t baseq = (size_t)b * TT * QS + (size_t)h * HD;
  const size_t baseo = (size_t)b * TT * DD + (size_t)h * HD;
  const int i0 = qgrp * 64 + wid * 16;
  const int g = lane >> 4;                  // 0..3
  const int c = lane & 15;

  const int i0b = qgrp * 64 + 48;
  const int ka0b = (i0b > 128) ? ((i0b - 128) & ~31) : 0;
  const int nlb = ((i0b + 16 - ka0b) + 31) >> 5;   // 1..5
  const int neb = (ka0b + 255) >> 8;
  const int ka0 = (i0 > 128) ? ((i0 - 128) & ~31) : 0;
  const int ne = (ka0 + 255) >> 8;                 // globals strictly below ka0

  const s16x8 qf0 = *(const s16x8*)&qkv[baseq + (size_t)(i0 + c) * QS + g * 8];
  const s16x8 qf1 = *(const s16x8*)&qkv[baseq + (size_t)(i0 + c) * QS + 32 + g * 8];

  f32x4 sc[NTMAX][2];
  float smax[4] = {-1e30f, -1e30f, -1e30f, -1e30f};

  // ---------------- pass 1: masked scaled scores ----------------
#pragma unroll
  for (int t = 0; t < NTMAX; t++) {
    if (t > nlb) continue;
    const bool isg = (t == 0);
    if (isg && neb == 0) continue;
    const int kt0 = ka0 + (t - 1) * 32;
#pragma unroll
    for (int it = 0; it < 4; it++) {
      const int row = it * 8 + (lane >> 3);
      const int ch = lane & 7;
      const int j = isg ? ((row < ne) ? row * STRIDE_G : 0) : (kt0 + row);
      *(s16x8*)&kvs[wid][row * KP + ch * 8] =
          *(const s16x8*)&qkv[baseq + DD + (size_t)j * QS + ch * 8];
    }
    __syncthreads();
#pragma unroll
    for (int half = 0; half < 2; half++) {
      const int key = half * 16 + c;
      const bf16x8 kb0 = __builtin_bit_cast(bf16x8, *(const s16x8*)&kvs[wid][key * KP + g * 8]);
      const bf16x8 kb1 = __builtin_bit_cast(bf16x8, *(const s16x8*)&kvs[wid][key * KP + 32 + g * 8]);
      f32x4 a = {};
      a = __builtin_amdgcn_mfma_f32_16x16x32_bf16(__builtin_bit_cast(bf16x8, qf0), kb0, a, 0, 0, 0);
      a = __builtin_amdgcn_mfma_f32_16x16x32_bf16(__builtin_bit_cast(bf16x8, qf1), kb1, a, 0, 0, 0);
#pragma unroll
      for (int r = 0; r < 4; r++) {
        const int i = i0 + g * 4 + r;
        bool ok;
        if (isg) {
          ok = (key < ne);
        } else {
          const int j = kt0 + key;
          ok = (j <= i) && (((i - j) <= LOCAL_W) || ((j & (STRIDE_G - 1)) == 0));
        }
        const float s = ok ? a[r] * 0.125f : -1e30f;
        sc[t][half][r] = s;
        smax[r] = fmaxf(smax[r], s);
      }
    }
    __syncthreads();
  }
#pragma unroll
  for (int r = 0; r < 4; r++)
#pragma unroll
    for (int off = 8; off; off >>= 1)
      smax[r] = fmaxf(smax[r], __shfl_xor(smax[r], off));

  // ---------------- pass 2: P = exp(s-m), O += P @ V ----------------
  f32x4 o[4] = {};
  float lsum[4] = {0.f, 0.f, 0.f, 0.f};
#pragma unroll
  for (int t = 0; t < NTMAX; t++) {
    if (t > nlb) continue;
    const bool isg = (t == 0);
    if (isg && neb == 0) continue;
    const int kt0 = ka0 + (t - 1) * 32;
#pragma unroll
    for (int it = 0; it < 4; it++) {
      const int row = it * 8 + (lane >> 3);
      const int ch = lane & 7;
      const int j = isg ? ((row < ne) ? row * STRIDE_G : 0) : (kt0 + row);
      *(s16x8*)&kvs[wid][row * KP + ch * 8] =
          *(const s16x8*)&qkv[baseq + 2 * DD + (size_t)j * QS + ch * 8];
    }
#pragma unroll
    for (int half = 0; half < 2; half++)
#pragma unroll
      for (int r = 0; r < 4; r++) {
        const float p = __expf(sc[t][half][r] - smax[r]);
        lsum[r] += p;
        pls[wid][(g * 4 + r) * PP + half * 16 + c] = f2b(p);
      }
    __syncthreads();
    const bf16x8 pa = __builtin_bit_cast(bf16x8, *(const s16x8*)&pls[wid][c * PP + g * 8]);
#pragma unroll
    for (int d0 = 0; d0 < 4; d0++) {
      s16x8 bv;
#pragma unroll
      for (int e = 0; e < 8; e++)
        bv[e] = (short)kvs[wid][(g * 8 + e) * KP + d0 * 16 + c];
      o[d0] = __builtin_amdgcn_mfma_f32_16x16x32_bf16(pa, __builtin_bit_cast(bf16x8, bv), o[d0], 0, 0, 0);
    }
    __syncthreads();
  }
#pragma unroll
  for (int r = 0; r < 4; r++)
#pragma unroll
    for (int off = 8; off; off >>= 1)
      lsum[r] += __shfl_xor(lsum[r], off);
#pragma unroll
  for (int d0 = 0; d0 < 4; d0++)
#pragma unroll
    for (int r = 0; r < 4; r++)
      outg[baseo + (size_t)(i0 + g * 4 + r) * DD + d0 * 16 + c] = f2b(o[d0][r] / lsum[r]);
}

// ---------------- host ----------------
extern "C" void kernel_launch(void* const* d_in, const int* in_sizes, int n_in,
                              void* d_out, int out_size, void* d_ws, size_t ws_size,
                              hipStream_t stream) {
  const int* x = (const int*)d_in[0];
  const float* embed = (const float*)d_in[1];
  const float* pos = (const float*)d_in[2];
  const float* Wq = (const float*)d_in[3];
  const float* bq = (const float*)d_in[4];
  const float* Wk = (const float*)d_in[5];
  const float* bk = (const float*)d_in[6];
  const float* Wv = (const float*)d_in[7];
  const float* bv = (const float*)d_in[8];
  const float* Wo = (const float*)d_in[9];
  const float* bo = (const float*)d_in[10];
  const float* g1 = (const float*)d_in[11];
  const float* be1 = (const float*)d_in[12];
  const float* W1 = (const float*)d_in[13];
  const float* bf1 = (const float*)d_in[14];
  const float* W2 = (const float*)d_in[15];
  const float* bf2 = (const float*)d_in[16];
  const float* g2 = (const float*)d_in[17];
  const float* be2 = (const float*)d_in[18];
  const float* gf = (const float*)d_in[19];
  const float* bef = (const float*)d_in[20];
  const float* Whead = (const float*)d_in[21];

  char* ws = (char*)d_ws;
  size_t off = 0;
  auto alloc = [&](size_t bytes) -> void* {
    void* p = ws + off;
    off += (bytes + 255) & ~(size_t)255;
    return p;
  };
  // weights (bf16, transposed)
  unsigned short* WqkvT = (unsigned short*)alloc((size_t)2 * QS * DD * 2);
  unsigned short* WoT = (unsigned short*)alloc((size_t)2 * DD * DD * 2);
  unsigned short* W1T = (unsigned short*)alloc((size_t)2 * DD * FF * 2);
  unsigned short* W2T = (unsigned short*)alloc((size_t)2 * DD * FF * 2);
  unsigned short* WheadT = (unsigned short*)alloc((size_t)DD * VV * 2);
  float* bcat = (float*)alloc((size_t)2 * QS * 4);
  // activations
  float* h = (float*)alloc((size_t)MM * DD * 4);
  unsigned short* hn = (unsigned short*)alloc((size_t)MM * DD * 2);
  unsigned short* qkvb = (unsigned short*)alloc((size_t)MM * QS * 2);   // 24 MB
  unsigned short* attnb = (unsigned short*)alloc((size_t)MM * DD * 2);  // 8 MB, contiguous after qkvb
  unsigned short* mid = (unsigned short*)alloc((size_t)MM * FF * 2);    // 32 MB
  // overlays (dead-buffer reuse):
  float* ffn2p = (float*)qkvb;  // 2 x [MM x DD] f32 = 32 MB = qkvb(24) + attnb(8)
  float* headp = (float*)mid;   // 4 x [MM x VV] f32 = 16 MB <= mid(32)
  (void)ws_size;

  const dim3 tb(32, 8);
  for (int l = 0; l < 2; l++) {
    const size_t wo = (size_t)l * DD * DD;
    const size_t wf = (size_t)l * DD * FF;
    // QKV weights into concatenated [3072][1024] per layer
    transpose_k<<<dim3(DD / 32, DD / 32), tb, 0, stream>>>(Wq + wo, WqkvT + (size_t)l * QS * DD, DD, DD);
    transpose_k<<<dim3(DD / 32, DD / 32), tb, 0, stream>>>(Wk + wo, WqkvT + ((size_t)l * QS + DD) * DD, DD, DD);
    transpose_k<<<dim3(DD / 32, DD / 32), tb, 0, stream>>>(Wv + wo, WqkvT + ((size_t)l * QS + 2 * DD) * DD, DD, DD);
    transpose_k<<<dim3(DD / 32, DD / 32), tb, 0, stream>>>(Wo + wo, WoT + wo, DD, DD);
    transpose_k<<<dim3(FF / 32, DD / 32), tb, 0, stream>>>(W1 + wf, W1T + wf, DD, FF);
    transpose_k<<<dim3(DD / 32, FF / 32), tb, 0, stream>>>(W2 + wf, W2T + wf, FF, DD);
  }
  transpose_k<<<dim3(VV / 32, DD / 32), tb, 0, stream>>>(Whead, WheadT, DD, VV);
  concat_bias<<<24, 256, 0, stream>>>(bq, bk, bv, bcat);

  embed_kernel<<<MM, 256, 0, stream>>>(x, embed, pos, h);

  for (int l = 0; l < 2; l++) {
    const size_t wo = (size_t)l * DD * DD;
    const size_t wf = (size_t)l * DD * FF;
    ln_kernel<<<MM, 256, 0, stream>>>(h, g1 + l * DD, be1 + l * DD, hn);
    // fused QKV: [4096,1024] x [3072,1024]^T -> [4096,3072]
    gemm_bt<1><<<(QS / 128) * (MM / 128), 512, 0, stream>>>(
        hn, WqkvT + (size_t)l * QS * DD, bcat + l * QS, nullptr, qkvb, MM, QS, DD, QS / 128);
    attn_mfma<<<BB * HH * (TT / 64), 256, 0, stream>>>(qkvb, attnb);
    gemm_bt<2><<<(DD / 128) * (MM / 128), 512, 0, stream>>>(
        attnb, WoT + wo, bo + l * DD, h, h, MM, DD, DD, DD / 128);
    ln_kernel<<<MM, 256, 0, stream>>>(h, g2 + l * DD, be2 + l * DD, hn);
    gemm_bt<3><<<(FF / 128) * (MM / 128), 512, 0, stream>>>(
        hn, W1T + wf, bf1 + l * FF, nullptr, mid, MM, FF, DD, FF / 128);
    // FFN2 split-K=2: partials then fused reduce (h += bf2 + P0 + P1)
    gemm_sk<<<2 * (DD / 128) * (MM / 128), 512, 0, stream>>>(
        mid, W2T + wf, ffn2p, MM, DD, FF, DD / 128, (DD / 128) * (MM / 128), FF / 2);
    reduce_k<2, true, true><<<(MM * DD) / 1024, 256, 0, stream>>>(
        h, ffn2p, bf2 + l * DD, DD, (size_t)MM * DD);
  }
  ln_kernel<<<MM, 256, 0, stream>>>(h, gf, bef, hn);
  // head split-K=4 -> d_out (f32)
  gemm_sk<<<4 * (VV / 128) * (MM / 128), 512, 0, stream>>>(
      hn, WheadT, headp, MM, VV, DD, VV / 128, (VV / 128) * (MM / 128), DD / 4);
  reduce_k<4, false, false><<<(MM * VV) / 1024, 256, 0, stream>>>(
      (float*)d_out, headp, nullptr, VV, (size_t)MM * VV);
}

// Round 5
// 472.273 us; speedup vs baseline: 2.6164x; 1.0816x over previous
//
#include <hip/hip_runtime.h>
#include <hip/hip_bf16.h>

// ---------------- problem constants ----------------
#define BB 2
#define TT 2048
#define DD 1024
#define FF 4096
#define VV 256
#define HH 16
#define HD 64
#define MM (BB * TT)      // 4096 rows
#define LOCAL_W 128
#define STRIDE_G 256
#define QS 3072           // fused QKV row stride

typedef short s16x8 __attribute__((ext_vector_type(8)));
typedef __bf16 bf16x8 __attribute__((ext_vector_type(8)));
typedef float f32x4 __attribute__((ext_vector_type(4)));

#define WAITVM(N) asm volatile("s_waitcnt vmcnt(" #N ")" ::: "memory")

__device__ __forceinline__ float b2f(unsigned short u) {
  return __builtin_bit_cast(float, (unsigned int)u << 16);
}
__device__ __forceinline__ unsigned short f2b(float f) {
  __hip_bfloat16 h = __float2bfloat16(f);  // RNE
  return __builtin_bit_cast(unsigned short, h);
}
// async global->LDS, 16B per lane; LDS dest = wave-uniform base + lane*16
__device__ __forceinline__ void gl_lds16(const unsigned short* g, unsigned short* l) {
  __builtin_amdgcn_global_load_lds(
      (const __attribute__((address_space(1))) void*)g,
      (__attribute__((address_space(3))) void*)l, 16, 0, 0);
}

// ---------------- weight transpose f32[K][N] -> bf16[N][K] ----------------
__global__ __launch_bounds__(256) void transpose_k(const float* __restrict__ W,
                                                   unsigned short* __restrict__ WT,
                                                   int K, int N) {
  __shared__ float t[32][33];
  const int n0 = blockIdx.x * 32, k0 = blockIdx.y * 32;
  const int tx = threadIdx.x, ty = threadIdx.y;  // (32, 8)
  for (int r = ty; r < 32; r += 8) t[r][tx] = W[(size_t)(k0 + r) * N + n0 + tx];
  __syncthreads();
  for (int r = ty; r < 32; r += 8)
    WT[(size_t)(n0 + r) * K + k0 + tx] = f2b(t[tx][r]);
}

// ---------------- concat QKV bias: bcat[l][3072] ----------------
__global__ __launch_bounds__(256) void concat_bias(const float* __restrict__ bq,
                                                   const float* __restrict__ bk,
                                                   const float* __restrict__ bv,
                                                   float* __restrict__ bcat) {
  const int i = blockIdx.x * 256 + threadIdx.x;  // 6144 total
  const int l = i / QS, j = i - l * QS;
  float v;
  if (j < DD) v = bq[l * DD + j];
  else if (j < 2 * DD) v = bk[l * DD + j - DD];
  else v = bv[l * DD + j - 2 * DD];
  bcat[i] = v;
}

// ---------------- embedding + positional ----------------
__global__ __launch_bounds__(256) void embed_kernel(const int* __restrict__ x,
                                                    const float* __restrict__ emb,
                                                    const float* __restrict__ pos,
                                                    float* __restrict__ h) {
  const int row = blockIdx.x;
  const int c = threadIdx.x * 4;
  const int tok = x[row];
  const int t = row & (TT - 1);
  float4 e = *(const float4*)&emb[(size_t)tok * DD + c];
  float4 p = *(const float4*)&pos[(size_t)t * DD + c];
  e.x += p.x; e.y += p.y; e.z += p.z; e.w += p.w;
  *(float4*)&h[(size_t)row * DD + c] = e;
}

// ---------------- layernorm f32 -> bf16 ----------------
__global__ __launch_bounds__(256) void ln_kernel(const float* __restrict__ x,
                                                 const float* __restrict__ g,
                                                 const float* __restrict__ be,
                                                 unsigned short* __restrict__ out) {
  const int row = blockIdx.x;
  const int tid = threadIdx.x;
  const float4 v = *(const float4*)&x[(size_t)row * DD + tid * 4];
  float s = v.x + v.y + v.z + v.w;
  float sq = v.x * v.x + v.y * v.y + v.z * v.z + v.w * v.w;
#pragma unroll
  for (int off = 32; off; off >>= 1) {
    s += __shfl_xor(s, off);
    sq += __shfl_xor(sq, off);
  }
  __shared__ float ss[4], ssq[4];
  const int w = tid >> 6, lane = tid & 63;
  if (lane == 0) { ss[w] = s; ssq[w] = sq; }
  __syncthreads();
  s = ss[0] + ss[1] + ss[2] + ss[3];
  sq = ssq[0] + ssq[1] + ssq[2] + ssq[3];
  const float mean = s * (1.0f / DD);
  const float var = sq * (1.0f / DD) - mean * mean;
  const float rstd = rsqrtf(var + 1e-5f);
  const float4 gv = *(const float4*)&g[tid * 4];
  const float4 bv = *(const float4*)&be[tid * 4];
  ushort4 o;
  o.x = f2b((v.x - mean) * rstd * gv.x + bv.x);
  o.y = f2b((v.y - mean) * rstd * gv.y + bv.y);
  o.z = f2b((v.z - mean) * rstd * gv.z + bv.z);
  o.w = f2b((v.w - mean) * rstd * gv.w + bv.w);
  *(ushort4*)&out[(size_t)row * DD + tid * 4] = o;
}

// ---------------- pipelined bf16 MFMA GEMM ----------------
// C = A[M,K] @ BT[N,K]^T, tiles BMxBM (BIG: 256, else 128), BK=32,
// 512 threads = 8 waves (2M x 4N). 4-deep circular LDS buffer, one raw
// s_barrier per K-tile, counted vmcnt (T3+T4), XOR chunk swizzle (T2,
// pre-swizzled global source per rule #21), setprio around MFMA (T5).
// XCD-swizzled flattened grid (nwg % 8 == 0). Split-K via nwg2/ksub.
// EPI: 0 = f32 split-K partial (no bias) at outp + ks*M*N
//      1 = bf16 out (+bias)
//      2 = f32 out (+bias + res)   (residual add; out may alias res)
//      3 = bf16 out, exact GELU(acc+bias)
template <int BIG, int EPI>
__global__ __launch_bounds__(512, 2) void gemm_p(const unsigned short* __restrict__ A,
                                                 const unsigned short* __restrict__ BT,
                                                 const float* __restrict__ bias,
                                                 const float* __restrict__ res,
                                                 void* __restrict__ outp,
                                                 int M, int N, int K, int nbx, int nwg2,
                                                 int ksub) {
  constexpr int BM = BIG ? 256 : 128;
  constexpr int MF = BIG ? 8 : 4;   // 16-row A fragments per wave
  constexpr int NF = BIG ? 4 : 2;   // 16-col B fragments per wave
  __shared__ __align__(16) unsigned short lds[4][BM * 64];  // per buf: A[BM*32] then B[BM*32]
  const int tid = threadIdx.x;
  const int lane = tid & 63;
  const int w = tid >> 6;  // 0..7
  const int nwg = gridDim.x;
  const int orig = blockIdx.x;
  const int wg = (orig & 7) * (nwg >> 3) + (orig >> 3);
  const int ks = wg / nwg2;
  const int rem = wg - ks * nwg2;
  const int n0 = (rem % nbx) * BM;
  const int m0 = (rem / nbx) * BM;
  const int kb = ks * ksub;
  const int wm = w >> 2, wn = w & 3;  // wave tile: (BM/2) rows x (BM/4) cols
  f32x4 acc[MF][NF] = {};

  // stage K-tile t into buf[t&3]; LDS linear, global source chunk pre-swizzled
  auto STAGE = [&](int t) {
    const int b = t & 3;
    const int kt = kb + (t << 5);
#pragma unroll
    for (int i = 0; i < (BIG ? 2 : 1); i++) {
      const int s = tid + (i << 9);          // 16B-chunk index
      const int row = s >> 2, sc = s & 3;
      const int c = sc ^ ((row >> 1) & 3);   // swizzled source chunk
      gl_lds16(&A[(size_t)(m0 + row) * K + kt + c * 8], &lds[b][s * 8]);
      gl_lds16(&BT[(size_t)(n0 + row) * K + kt + c * 8], &lds[b][BM * 32 + s * 8]);
    }
  };

  const int NT = ksub >> 5;  // >= 8 for all our shapes
  STAGE(0); STAGE(1); STAGE(2);

  for (int t = 0; t < NT; ++t) {
    const int ahead = NT - 1 - t;  // staged tiles allowed to stay in flight
    if (BIG) {
      if (ahead >= 2) WAITVM(8); else if (ahead == 1) WAITVM(4); else WAITVM(0);
    } else {
      if (ahead >= 2) WAITVM(4); else if (ahead == 1) WAITVM(2); else WAITVM(0);
    }
    __builtin_amdgcn_s_barrier();
    asm volatile("" ::: "memory");
    if (t + 3 < NT) STAGE(t + 3);  // overwrites buf last read at tile t-1: safe post-barrier
    const int b = t & 3;
    const int rA = lane & 15, cr = lane >> 4;
    bf16x8 af[MF], bfr[NF];
#pragma unroll
    for (int m = 0; m < MF; m++) {
      const int row = wm * (BM / 2) + m * 16 + rA;
      af[m] = __builtin_bit_cast(
          bf16x8, *(const s16x8*)&lds[b][row * 32 + ((cr ^ ((row >> 1) & 3)) << 3)]);
    }
#pragma unroll
    for (int n = 0; n < NF; n++) {
      const int row = wn * (BM / 4) + n * 16 + rA;
      bfr[n] = __builtin_bit_cast(
          bf16x8, *(const s16x8*)&lds[b][BM * 32 + row * 32 + ((cr ^ ((row >> 1) & 3)) << 3)]);
    }
    __builtin_amdgcn_s_setprio(1);
#pragma unroll
    for (int m = 0; m < MF; m++)
#pragma unroll
      for (int n = 0; n < NF; n++)
        acc[m][n] = __builtin_amdgcn_mfma_f32_16x16x32_bf16(af[m], bfr[n], acc[m][n], 0, 0, 0);
    __builtin_amdgcn_s_setprio(0);
  }

  const int r0 = (lane >> 4) * 4;
  const int cc = lane & 15;
  float* pout = (EPI == 0) ? ((float*)outp + (size_t)ks * M * N) : (float*)outp;
#pragma unroll
  for (int m = 0; m < MF; m++) {
#pragma unroll
    for (int n = 0; n < NF; n++) {
#pragma unroll
      for (int r = 0; r < 4; r++) {
        const int row = m0 + wm * (BM / 2) + m * 16 + r0 + r;
        const int col = n0 + wn * (BM / 4) + n * 16 + cc;
        const size_t idx = (size_t)row * N + col;
        if (EPI == 0) {
          pout[idx] = acc[m][n][r];
        } else {
          float val = acc[m][n][r] + bias[col];
          if (EPI == 1) {
            ((unsigned short*)outp)[idx] = f2b(val);
          } else if (EPI == 2) {
            ((float*)outp)[idx] = val + res[idx];
          } else {
            const float gv = 0.5f * val * (1.0f + erff(val * 0.70710678118654752f));
            ((unsigned short*)outp)[idx] = f2b(gv);
          }
        }
      }
    }
  }
}

// ---------------- reduce: dst = (RES? dst) + (BIAS? bias) + sum(parts) ----------------
template <int NP, bool BIAS, bool RES>
__global__ __launch_bounds__(256) void reduce_k(float* __restrict__ dst,
                                                const float* __restrict__ parts,
                                                const float* __restrict__ bias,
                                                int ncols, size_t total) {
  const size_t i = ((size_t)blockIdx.x * 256 + threadIdx.x) * 4;
  if (i >= total) return;
  f32x4 acc = {};
  if (RES) acc = *(const f32x4*)&dst[i];
  if (BIAS) {
    const int col = (int)(i % ncols);
    acc += *(const f32x4*)&bias[col];
  }
#pragma unroll
  for (int p = 0; p < NP; p++) acc += *(const f32x4*)&parts[(size_t)p * total + i];
  *(f32x4*)&dst[i] = acc;
}

// ---------------- MFMA sparse attention (fused-QKV input, stride QS) ----------------
#define QT 16
#define KT 32
#define NTMAX 6
#define KP 72   // padded K/V tile row (shorts)
#define PP 40   // padded P row (shorts)

__global__ __launch_bounds__(256) void attn_mfma(const unsigned short* __restrict__ qkv,
                                                 unsigned short* __restrict__ outg) {
  __shared__ __align__(16) unsigned short kvs[4][KT * KP];
  __shared__ __align__(16) unsigned short pls[4][QT * PP];
  const int tid = threadIdx.x;
  const int wid = tid >> 6, lane = tid & 63;
  const int qgrp = blockIdx.x & 31;         // 64-query group within (b,h)
  const int bh = blockIdx.x >> 5;
  const int h = bh & (HH - 1), b = bh >> 4;
  const size_t baseq = (size_t)b * TT * QS + (size_t)h * HD;
  const size_t baseo = (size_t)b * TT * DD + (size_t)h * HD;
  const int i0 = qgrp * 64 + wid * 16;
  const int g = lane >> 4;                  // 0..3
  const int c = lane & 15;

  const int i0b = qgrp * 64 + 48;
  const int ka0b = (i0b > 128) ? ((i0b - 128) & ~31) : 0;
  const int nlb = ((i0b + 16 - ka0b) + 31) >> 5;   // 1..5
  const int neb = (ka0b + 255) >> 8;
  const int ka0 = (i0 > 128) ? ((i0 - 128) & ~31) : 0;
  const int ne = (ka0 + 255) >> 8;                 // globals strictly below ka0

  const s16x8 qf0 = *(const s16x8*)&qkv[baseq + (size_t)(i0 + c) * QS + g * 8];
  const s16x8 qf1 = *(const s16x8*)&qkv[baseq + (size_t)(i0 + c) * QS + 32 + g * 8];

  f32x4 sc[NTMAX][2];
  float smax[4] = {-1e30f, -1e30f, -1e30f, -1e30f};

  // ---------------- pass 1: masked scaled scores ----------------
#pragma unroll
  for (int t = 0; t < NTMAX; t++) {
    if (t > nlb) continue;
    const bool isg = (t == 0);
    if (isg && neb == 0) continue;
    const int kt0 = ka0 + (t - 1) * 32;
#pragma unroll
    for (int it = 0; it < 4; it++) {
      const int row = it * 8 + (lane >> 3);
      const int ch = lane & 7;
      const int j = isg ? ((row < ne) ? row * STRIDE_G : 0) : (kt0 + row);
      *(s16x8*)&kvs[wid][row * KP + ch * 8] =
          *(const s16x8*)&qkv[baseq + DD + (size_t)j * QS + ch * 8];
    }
    __syncthreads();
#pragma unroll
    for (int half = 0; half < 2; half++) {
      const int key = half * 16 + c;
      const bf16x8 kb0 = __builtin_bit_cast(bf16x8, *(const s16x8*)&kvs[wid][key * KP + g * 8]);
      const bf16x8 kb1 = __builtin_bit_cast(bf16x8, *(const s16x8*)&kvs[wid][key * KP + 32 + g * 8]);
      f32x4 a = {};
      a = __builtin_amdgcn_mfma_f32_16x16x32_bf16(__builtin_bit_cast(bf16x8, qf0), kb0, a, 0, 0, 0);
      a = __builtin_amdgcn_mfma_f32_16x16x32_bf16(__builtin_bit_cast(bf16x8, qf1), kb1, a, 0, 0, 0);
#pragma unroll
      for (int r = 0; r < 4; r++) {
        const int i = i0 + g * 4 + r;
        bool ok;
        if (isg) {
          ok = (key < ne);
        } else {
          const int j = kt0 + key;
          ok = (j <= i) && (((i - j) <= LOCAL_W) || ((j & (STRIDE_G - 1)) == 0));
        }
        const float s = ok ? a[r] * 0.125f : -1e30f;
        sc[t][half][r] = s;
        smax[r] = fmaxf(smax[r], s);
      }
    }
    __syncthreads();
  }
#pragma unroll
  for (int r = 0; r < 4; r++)
#pragma unroll
    for (int off = 8; off; off >>= 1)
      smax[r] = fmaxf(smax[r], __shfl_xor(smax[r], off));

  // ---------------- pass 2: P = exp(s-m), O += P @ V ----------------
  f32x4 o[4] = {};
  float lsum[4] = {0.f, 0.f, 0.f, 0.f};
#pragma unroll
  for (int t = 0; t < NTMAX; t++) {
    if (t > nlb) continue;
    const bool isg = (t == 0);
    if (isg && neb == 0) continue;
    const int kt0 = ka0 + (t - 1) * 32;
#pragma unroll
    for (int it = 0; it < 4; it++) {
      const int row = it * 8 + (lane >> 3);
      const int ch = lane & 7;
      const int j = isg ? ((row < ne) ? row * STRIDE_G : 0) : (kt0 + row);
      *(s16x8*)&kvs[wid][row * KP + ch * 8] =
          *(const s16x8*)&qkv[baseq + 2 * DD + (size_t)j * QS + ch * 8];
    }
#pragma unroll
    for (int half = 0; half < 2; half++)
#pragma unroll
      for (int r = 0; r < 4; r++) {
        const float p = __expf(sc[t][half][r] - smax[r]);
        lsum[r] += p;
        pls[wid][(g * 4 + r) * PP + half * 16 + c] = f2b(p);
      }
    __syncthreads();
    const bf16x8 pa = __builtin_bit_cast(bf16x8, *(const s16x8*)&pls[wid][c * PP + g * 8]);
#pragma unroll
    for (int d0 = 0; d0 < 4; d0++) {
      s16x8 bv;
#pragma unroll
      for (int e = 0; e < 8; e++)
        bv[e] = (short)kvs[wid][(g * 8 + e) * KP + d0 * 16 + c];
      o[d0] = __builtin_amdgcn_mfma_f32_16x16x32_bf16(pa, __builtin_bit_cast(bf16x8, bv), o[d0], 0, 0, 0);
    }
    __syncthreads();
  }
#pragma unroll
  for (int r = 0; r < 4; r++)
#pragma unroll
    for (int off = 8; off; off >>= 1)
      lsum[r] += __shfl_xor(lsum[r], off);
#pragma unroll
  for (int d0 = 0; d0 < 4; d0++)
#pragma unroll
    for (int r = 0; r < 4; r++)
      outg[baseo + (size_t)(i0 + g * 4 + r) * DD + d0 * 16 + c] = f2b(o[d0][r] / lsum[r]);
}

// ---------------- host ----------------
extern "C" void kernel_launch(void* const* d_in, const int* in_sizes, int n_in,
                              void* d_out, int out_size, void* d_ws, size_t ws_size,
                              hipStream_t stream) {
  const int* x = (const int*)d_in[0];
  const float* embed = (const float*)d_in[1];
  const float* pos = (const float*)d_in[2];
  const float* Wq = (const float*)d_in[3];
  const float* bq = (const float*)d_in[4];
  const float* Wk = (const float*)d_in[5];
  const float* bk = (const float*)d_in[6];
  const float* Wv = (const float*)d_in[7];
  const float* bv = (const float*)d_in[8];
  const float* Wo = (const float*)d_in[9];
  const float* bo = (const float*)d_in[10];
  const float* g1 = (const float*)d_in[11];
  const float* be1 = (const float*)d_in[12];
  const float* W1 = (const float*)d_in[13];
  const float* bf1 = (const float*)d_in[14];
  const float* W2 = (const float*)d_in[15];
  const float* bf2 = (const float*)d_in[16];
  const float* g2 = (const float*)d_in[17];
  const float* be2 = (const float*)d_in[18];
  const float* gf = (const float*)d_in[19];
  const float* bef = (const float*)d_in[20];
  const float* Whead = (const float*)d_in[21];

  char* ws = (char*)d_ws;
  size_t off = 0;
  auto alloc = [&](size_t bytes) -> void* {
    void* p = ws + off;
    off += (bytes + 255) & ~(size_t)255;
    return p;
  };
  // weights (bf16, transposed)
  unsigned short* WqkvT = (unsigned short*)alloc((size_t)2 * QS * DD * 2);
  unsigned short* WoT = (unsigned short*)alloc((size_t)2 * DD * DD * 2);
  unsigned short* W1T = (unsigned short*)alloc((size_t)2 * DD * FF * 2);
  unsigned short* W2T = (unsigned short*)alloc((size_t)2 * DD * FF * 2);
  unsigned short* WheadT = (unsigned short*)alloc((size_t)DD * VV * 2);
  float* bcat = (float*)alloc((size_t)2 * QS * 4);
  // activations
  float* h = (float*)alloc((size_t)MM * DD * 4);
  unsigned short* hn = (unsigned short*)alloc((size_t)MM * DD * 2);
  unsigned short* qkvb = (unsigned short*)alloc((size_t)MM * QS * 2);   // 24 MB
  unsigned short* attnb = (unsigned short*)alloc((size_t)MM * DD * 2);  // 8 MB, contiguous after qkvb
  unsigned short* mid = (unsigned short*)alloc((size_t)MM * FF * 2);    // 32 MB
  // overlays (dead-buffer reuse):
  float* ffn2p = (float*)qkvb;  // 2 x [MM x DD] f32 = 32 MB = qkvb(24) + attnb(8)
  float* headp = (float*)mid;   // 4 x [MM x VV] f32 = 16 MB <= mid(32)
  (void)ws_size;

  const dim3 tb(32, 8);
  for (int l = 0; l < 2; l++) {
    const size_t wo = (size_t)l * DD * DD;
    const size_t wf = (size_t)l * DD * FF;
    // QKV weights into concatenated [3072][1024] per layer
    transpose_k<<<dim3(DD / 32, DD / 32), tb, 0, stream>>>(Wq + wo, WqkvT + (size_t)l * QS * DD, DD, DD);
    transpose_k<<<dim3(DD / 32, DD / 32), tb, 0, stream>>>(Wk + wo, WqkvT + ((size_t)l * QS + DD) * DD, DD, DD);
    transpose_k<<<dim3(DD / 32, DD / 32), tb, 0, stream>>>(Wv + wo, WqkvT + ((size_t)l * QS + 2 * DD) * DD, DD, DD);
    transpose_k<<<dim3(DD / 32, DD / 32), tb, 0, stream>>>(Wo + wo, WoT + wo, DD, DD);
    transpose_k<<<dim3(FF / 32, DD / 32), tb, 0, stream>>>(W1 + wf, W1T + wf, DD, FF);
    transpose_k<<<dim3(DD / 32, FF / 32), tb, 0, stream>>>(W2 + wf, W2T + wf, FF, DD);
  }
  transpose_k<<<dim3(VV / 32, DD / 32), tb, 0, stream>>>(Whead, WheadT, DD, VV);
  concat_bias<<<24, 256, 0, stream>>>(bq, bk, bv, bcat);

  embed_kernel<<<MM, 256, 0, stream>>>(x, embed, pos, h);

  for (int l = 0; l < 2; l++) {
    const size_t wo = (size_t)l * DD * DD;
    const size_t wf = (size_t)l * DD * FF;
    ln_kernel<<<MM, 256, 0, stream>>>(h, g1 + l * DD, be1 + l * DD, hn);
    // fused QKV: [4096,1024] x [3072,1024]^T -> [4096,3072]; 256^2 tiles, grid 192
    gemm_p<1, 1><<<(QS / 256) * (MM / 256), 512, 0, stream>>>(
        hn, WqkvT + (size_t)l * QS * DD, bcat + l * QS, nullptr, qkvb,
        MM, QS, DD, QS / 256, (QS / 256) * (MM / 256), DD);
    attn_mfma<<<BB * HH * (TT / 64), 256, 0, stream>>>(qkvb, attnb);
    // O-proj: 128^2 tiles, grid 256
    gemm_p<0, 2><<<(DD / 128) * (MM / 128), 512, 0, stream>>>(
        attnb, WoT + wo, bo + l * DD, h, h,
        MM, DD, DD, DD / 128, (DD / 128) * (MM / 128), DD);
    ln_kernel<<<MM, 256, 0, stream>>>(h, g2 + l * DD, be2 + l * DD, hn);
    // FFN1: 256^2 tiles, grid 256
    gemm_p<1, 3><<<(FF / 256) * (MM / 256), 512, 0, stream>>>(
        hn, W1T + wf, bf1 + l * FF, nullptr, mid,
        MM, FF, DD, FF / 256, (FF / 256) * (MM / 256), DD);
    // FFN2 split-K=2: partials then fused reduce (h += bf2 + P0 + P1)
    gemm_p<0, 0><<<2 * (DD / 128) * (MM / 128), 512, 0, stream>>>(
        mid, W2T + wf, nullptr, nullptr, ffn2p,
        MM, DD, FF, DD / 128, (DD / 128) * (MM / 128), FF / 2);
    reduce_k<2, true, true><<<(MM * DD) / 1024, 256, 0, stream>>>(
        h, ffn2p, bf2 + l * DD, DD, (size_t)MM * DD);
  }
  ln_kernel<<<MM, 256, 0, stream>>>(h, gf, bef, hn);
  // head split-K=4 -> partials -> d_out (f32)
  gemm_p<0, 0><<<4 * (VV / 128) * (MM / 128), 512, 0, stream>>>(
      hn, WheadT, nullptr, nullptr, headp,
      MM, VV, DD, VV / 128, (VV / 128) * (MM / 128), DD / 4);
  reduce_k<4, false, false><<<(MM * VV) / 1024, 256, 0, stream>>>(
      (float*)d_out, headp, nullptr, VV, (size_t)MM * VV);
}